// Round 13
// baseline (235.762 us; speedup 1.0000x reference)
//
#include <hip/hip_runtime.h>
#include <math.h>

#define LQ 512
#define CN 384
#define CE 128
#define CH 192
#define NG 12
#define PPG 16
#define FEAT 2112
#define NPROJ 1152
#define WLs 0.5773502691896258f

// ws float offsets
#define WS_RAW  0u         // [l][1152]
#define WS_QVG  589824u    // [l][144]
#define WS_KVT  663552u    // [144][512]
#define WS_VVG  737280u    // [l][288]
#define WS_QN   884736u    // [l][12]
#define WS_KNT  890880u    // [12][512]
#define WS_KT   897024u    // [192][512]
#define WS_ATT  995328u    // [i][12][512] TRANSPOSED NORMALIZED attention
#define WS_FEAT 4141056u   // [i][2112]
#define WS_PART 5222400u   // [3][512][384] (k4/k5 only)
#define WS_WBT  5836800u   // [12][128] transposed Wbias
#define WS_LGS  5861376u   // [i][j][12] base logits

// ---------------- K0: transpose Wbias -> wbT[12][128] ----------------
__global__ __launch_bounds__(256) void k0_wbt(const float* __restrict__ Wbias,
                                              float* __restrict__ ws)
{
    int idx = blockIdx.x * 256 + threadIdx.x;
    if (idx < CE * NG) {
        int c = idx / NG, g = idx % NG;
        ws[WS_WBT + g * CE + c] = Wbias[idx];
    }
}

// ---------------- K1a: tiled projection GEMM -> raw (+KT transposed copy) ----------------
__global__ __launch_bounds__(256) void k1a_gemm(
    const float* __restrict__ Node,
    const float* __restrict__ Wq, const float* __restrict__ Wk,
    const float* __restrict__ Wv, const float* __restrict__ Wqv,
    const float* __restrict__ Wkv, const float* __restrict__ Wvv,
    float* __restrict__ ws)
{
    __shared__ float As[64][68];
    __shared__ float Bs[64][48];
    const int tid = threadIdx.x;
    const int cb = blockIdx.x % 24;
    const int l0 = (blockIdx.x / 24) * 64;
    const int col0 = cb * 48;

    const float* W; int nc, lc0;
    if (col0 < 192)      { W = Wq;  nc = 192; lc0 = col0; }
    else if (col0 < 384) { W = Wk;  nc = 192; lc0 = col0 - 192; }
    else if (col0 < 576) { W = Wv;  nc = 192; lc0 = col0 - 384; }
    else if (col0 < 720) { W = Wqv; nc = 144; lc0 = col0 - 576; }
    else if (col0 < 864) { W = Wkv; nc = 144; lc0 = col0 - 720; }
    else                 { W = Wvv; nc = 288; lc0 = col0 - 864; }

    const int tx = tid & 15, ty = tid >> 4;
    float acc[4][3];
#pragma unroll
    for (int r = 0; r < 4; ++r)
#pragma unroll
        for (int c = 0; c < 3; ++c) acc[r][c] = 0.f;

    for (int kc = 0; kc < 6; ++kc) {
        __syncthreads();
#pragma unroll
        for (int pass = 0; pass < 4; ++pass) {
            int m = (tid >> 4) + pass * 16;
            int kk = (tid & 15) * 4;
            const float4 a = *(const float4*)(Node + (size_t)(l0 + m) * CN + kc * 64 + kk);
            As[kk + 0][m] = a.x; As[kk + 1][m] = a.y;
            As[kk + 2][m] = a.z; As[kk + 3][m] = a.w;
        }
#pragma unroll
        for (int p = 0; p < 12; ++p) {
            int idx = p * 256 + tid;
            int kk = idx / 48, c = idx - kk * 48;
            Bs[kk][c] = W[(size_t)(kc * 64 + kk) * nc + lc0 + c];
        }
        __syncthreads();
#pragma unroll 8
        for (int kk = 0; kk < 64; ++kk) {
            const float4 av = *(const float4*)&As[kk][tx * 4];
            const float b0 = Bs[kk][ty * 3 + 0];
            const float b1 = Bs[kk][ty * 3 + 1];
            const float b2 = Bs[kk][ty * 3 + 2];
            acc[0][0] = fmaf(av.x, b0, acc[0][0]); acc[0][1] = fmaf(av.x, b1, acc[0][1]); acc[0][2] = fmaf(av.x, b2, acc[0][2]);
            acc[1][0] = fmaf(av.y, b0, acc[1][0]); acc[1][1] = fmaf(av.y, b1, acc[1][1]); acc[1][2] = fmaf(av.y, b2, acc[1][2]);
            acc[2][0] = fmaf(av.z, b0, acc[2][0]); acc[2][1] = fmaf(av.z, b1, acc[2][1]); acc[2][2] = fmaf(av.z, b2, acc[2][2]);
            acc[3][0] = fmaf(av.w, b0, acc[3][0]); acc[3][1] = fmaf(av.w, b1, acc[3][1]); acc[3][2] = fmaf(av.w, b2, acc[3][2]);
        }
    }
    float* raw = ws + WS_RAW;
#pragma unroll
    for (int r = 0; r < 4; ++r)
#pragma unroll
        for (int c = 0; c < 3; ++c)
            raw[(size_t)(l0 + tx * 4 + r) * NPROJ + col0 + ty * 3 + c] = acc[r][c];
    if (col0 >= 192 && col0 < 384) {
#pragma unroll
        for (int r = 0; r < 4; ++r)
#pragma unroll
            for (int c = 0; c < 3; ++c)
                ws[WS_KT + (size_t)(col0 - 192 + ty * 3 + c) * LQ + l0 + tx * 4 + r] = acc[r][c];
    }
}

// ---------------- K1b: frame apply + point norms ----------------
__global__ __launch_bounds__(256) void k1b_vec(
    const float* __restrict__ rots, const float* __restrict__ trans,
    float* __restrict__ ws)
{
    __shared__ float sqbuf[96];
    const int tid = threadIdx.x;
    const int l = blockIdx.x;
    const float* raw = ws + WS_RAW + (size_t)l * NPROJ;

    if (tid < 192) {
        int src, pt, typ;
        if (tid < 48)      { typ = 0; pt = tid;      src = 576 + pt * 3; }
        else if (tid < 96) { typ = 1; pt = tid - 48; src = 720 + pt * 3; }
        else               { typ = 2; pt = tid - 96; src = 864 + pt * 3; }
        float v0 = raw[src], v1 = raw[src + 1], v2 = raw[src + 2];
        const float* R = rots + l * 9;
        float o0 = R[0] * v0 + R[1] * v1 + R[2] * v2 + trans[l * 3 + 0] * 0.1f;
        float o1 = R[3] * v0 + R[4] * v1 + R[5] * v2 + trans[l * 3 + 1] * 0.1f;
        float o2 = R[6] * v0 + R[7] * v1 + R[8] * v2 + trans[l * 3 + 2] * 0.1f;
        if (typ == 0) {
            float* dst = ws + WS_QVG + (size_t)l * 144 + pt * 3;
            dst[0] = o0; dst[1] = o1; dst[2] = o2;
        } else if (typ == 1) {
            ws[WS_KVT + (size_t)(pt * 3 + 0) * LQ + l] = o0;
            ws[WS_KVT + (size_t)(pt * 3 + 1) * LQ + l] = o1;
            ws[WS_KVT + (size_t)(pt * 3 + 2) * LQ + l] = o2;
        } else {
            float* dst = ws + WS_VVG + (size_t)l * 288 + pt * 3;
            dst[0] = o0; dst[1] = o1; dst[2] = o2;
        }
        if (tid < 96) sqbuf[tid] = o0 * o0 + o1 * o1 + o2 * o2;
    }
    __syncthreads();
    if (tid < 24) {
        int typ = tid / 12, g = tid % 12;
        int b = typ * 48 + g * 4;
        float s = sqbuf[b] + sqbuf[b + 1] + sqbuf[b + 2] + sqbuf[b + 3];
        if (typ == 0) ws[WS_QN + (size_t)l * 12 + g] = s;
        else          ws[WS_KNT + (size_t)g * LQ + l] = s;
    }
}

// ---------------- K2a: base logits -> LGS ----------------
__global__ __launch_bounds__(256) void k2a_logits(
    const float* __restrict__ gamma, float* __restrict__ ws)
{
    __shared__ float cgls[NG];
    const int tid = threadIdx.x;
    const int i = blockIdx.x >> 1;
    const int h = blockIdx.x & 1;
    const int j = h * 256 + tid;

    if (tid < NG)
        cgls[tid] = log1pf(__expf(gamma[tid])) * 0.11785113019775793f;
    __syncthreads();

    const float* qrow  = ws + WS_RAW + (size_t)i * NPROJ;
    const float* qvrow = ws + WS_QVG + (size_t)i * 144;
    const float* qnrow = ws + WS_QN  + (size_t)i * NG;
    const float* KT  = ws + WS_KT;
    const float* KVT = ws + WS_KVT;
    const float* KNT = ws + WS_KNT;
    float lgs[NG];
#pragma unroll
    for (int g = 0; g < NG; ++g) {
        float qk = 0.f;
#pragma unroll
        for (int u = 0; u < PPG; ++u)
            qk = fmaf(qrow[g * PPG + u], KT[(size_t)(g * PPG + u) * LQ + j], qk);
        float dt = 0.f;
#pragma unroll
        for (int u = 0; u < 12; ++u)
            dt = fmaf(qvrow[g * 12 + u], KVT[(size_t)(g * 12 + u) * LQ + j], dt);
        float sq = qnrow[g] + KNT[(size_t)g * LQ + j] - 2.f * dt;
        lgs[g] = qk * 0.25f - cgls[g] * sq;
    }
    float4* dst = (float4*)(ws + WS_LGS + ((size_t)i * LQ + j) * NG);
    float4 s0, s1, s2;
    s0.x = lgs[0]; s0.y = lgs[1]; s0.z = lgs[2];  s0.w = lgs[3];
    s1.x = lgs[4]; s1.y = lgs[5]; s1.z = lgs[6];  s1.w = lgs[7];
    s2.x = lgs[8]; s2.y = lgs[9]; s2.z = lgs[10]; s2.w = lgs[11];
    dst[0] = s0; dst[1] = s1; dst[2] = s2;
}

// ---------------- K2b: bias + full softmax per i -> normalized ATT_T ----------------
// block = query row i; thread owns j = tid and tid+256 (W reads amortized 2x).
__global__ __launch_bounds__(256, 3) void k2b_bias(
    const float* __restrict__ Edge, float* __restrict__ ws)
{
    __shared__ float wbs[NG * CE];    // 6 KB  [g][c]
    __shared__ float et[LQ * 17];     // 34 KB: 16-ch chunk per row (+1 pad)
    __shared__ float red[4][NG];
    const int tid = threadIdx.x;
    const int i = blockIdx.x;

    for (int u = tid; u < NG * CE; u += 256) wbs[u] = ws[WS_WBT + u];

    // base logits for this thread's two rows
    float lgs0[NG], lgs1[NG];
    {
        const float4* a4 = (const float4*)(ws + WS_LGS + ((size_t)i * LQ + tid) * NG);
        const float4* b4 = (const float4*)(ws + WS_LGS + ((size_t)i * LQ + tid + 256) * NG);
        float4 A0 = a4[0], A1 = a4[1], A2 = a4[2];
        float4 B0 = b4[0], B1 = b4[1], B2 = b4[2];
        lgs0[0]=A0.x; lgs0[1]=A0.y; lgs0[2]=A0.z;  lgs0[3]=A0.w;
        lgs0[4]=A1.x; lgs0[5]=A1.y; lgs0[6]=A1.z;  lgs0[7]=A1.w;
        lgs0[8]=A2.x; lgs0[9]=A2.y; lgs0[10]=A2.z; lgs0[11]=A2.w;
        lgs1[0]=B0.x; lgs1[1]=B0.y; lgs1[2]=B0.z;  lgs1[3]=B0.w;
        lgs1[4]=B1.x; lgs1[5]=B1.y; lgs1[6]=B1.z;  lgs1[7]=B1.w;
        lgs1[8]=B2.x; lgs1[9]=B2.y; lgs1[10]=B2.z; lgs1[11]=B2.w;
    }

    const float4* e4 = (const float4*)(Edge + (size_t)i * LQ * CE);  // row stride 32 f4
    float4 buf[8];

    // prologue: chunk 0 (channels 0..15) -> regs -> LDS
#pragma unroll
    for (int t = 0; t < 8; ++t) {
        int idx = t * 256 + tid;              // 0..2047
        int row = idx >> 2, cq = idx & 3;
        buf[t] = e4[(size_t)row * 32 + cq];
    }
#pragma unroll
    for (int t = 0; t < 8; ++t) {
        int idx = t * 256 + tid;
        int row = idx >> 2, cq = idx & 3;
        float* d = et + row * 17 + cq * 4;
        d[0] = buf[t].x; d[1] = buf[t].y; d[2] = buf[t].z; d[3] = buf[t].w;
    }
    __syncthreads();

    for (int ch = 0; ch < 8; ++ch) {
        if (ch < 7) {
#pragma unroll
            for (int t = 0; t < 8; ++t) {
                int idx = t * 256 + tid;
                int row = idx >> 2, cq = idx & 3;
                buf[t] = e4[(size_t)row * 32 + (ch + 1) * 4 + cq];
            }
        }
        const float* r0 = et + tid * 17;
        const float* r1 = et + (tid + 256) * 17;
#pragma unroll
        for (int cq = 0; cq < 4; ++cq) {
            float e0 = r0[cq * 4 + 0], e1 = r0[cq * 4 + 1];
            float e2 = r0[cq * 4 + 2], e3 = r0[cq * 4 + 3];
            float f0 = r1[cq * 4 + 0], f1 = r1[cq * 4 + 1];
            float f2 = r1[cq * 4 + 2], f3 = r1[cq * 4 + 3];
#pragma unroll
            for (int g = 0; g < NG; ++g) {
                const float4 wv = *(const float4*)&wbs[g * CE + ch * 16 + cq * 4];
                float s0 = lgs0[g], s1 = lgs1[g];
                s0 = fmaf(e0, wv.x, s0); s0 = fmaf(e1, wv.y, s0);
                s0 = fmaf(e2, wv.z, s0); s0 = fmaf(e3, wv.w, s0);
                s1 = fmaf(f0, wv.x, s1); s1 = fmaf(f1, wv.y, s1);
                s1 = fmaf(f2, wv.z, s1); s1 = fmaf(f3, wv.w, s1);
                lgs0[g] = s0; lgs1[g] = s1;
            }
        }
        __syncthreads();
        if (ch < 7) {
#pragma unroll
            for (int t = 0; t < 8; ++t) {
                int idx = t * 256 + tid;
                int row = idx >> 2, cq = idx & 3;
                float* d = et + row * 17 + cq * 4;
                d[0] = buf[t].x; d[1] = buf[t].y; d[2] = buf[t].z; d[3] = buf[t].w;
            }
            __syncthreads();
        }
    }

    // full softmax over all 512 j (in-block)
    const int wid = tid >> 6, lane = tid & 63;
    float pm[NG];
#pragma unroll
    for (int g = 0; g < NG; ++g) pm[g] = fmaxf(lgs0[g], lgs1[g]);
#pragma unroll
    for (int g = 0; g < NG; ++g)
        for (int off = 1; off < 64; off <<= 1)
            pm[g] = fmaxf(pm[g], __shfl_xor(pm[g], off));
    if (lane == 0) {
#pragma unroll
        for (int g = 0; g < NG; ++g) red[wid][g] = pm[g];
    }
    __syncthreads();
    float gm[NG];
#pragma unroll
    for (int g = 0; g < NG; ++g)
        gm[g] = fmaxf(fmaxf(red[0][g], red[1][g]), fmaxf(red[2][g], red[3][g]));
    __syncthreads();

    float ps[NG];
#pragma unroll
    for (int g = 0; g < NG; ++g) {
        float ea = __expf(WLs * (lgs0[g] - gm[g]));
        float eb = __expf(WLs * (lgs1[g] - gm[g]));
        lgs0[g] = ea; lgs1[g] = eb;
        ps[g] = ea + eb;
    }
#pragma unroll
    for (int g = 0; g < NG; ++g)
        for (int off = 1; off < 64; off <<= 1)
            ps[g] += __shfl_xor(ps[g], off);
    if (lane == 0) {
#pragma unroll
        for (int g = 0; g < NG; ++g) red[wid][g] = ps[g];
    }
    __syncthreads();

    float* attT = ws + WS_ATT + (size_t)i * (NG * LQ);
#pragma unroll
    for (int g = 0; g < NG; ++g) {
        float inv = 1.f / (red[0][g] + red[1][g] + red[2][g] + red[3][g]);
        attT[g * LQ + tid] = lgs0[g] * inv;
        attT[g * LQ + tid + 256] = lgs1[g] * inv;
    }
}

// ---------------- K3a: O_Edge (single Edge stream, b128 at-reads) ----------------
__global__ __launch_bounds__(256) void k3a_oedge(
    const float* __restrict__ Edge, float* __restrict__ ws)
{
    __shared__ float atls[NG * 516];
    __shared__ float bufA[4][32][NG][4];
    const int tid = threadIdx.x;
    const int qi = blockIdx.x;

    const float4* attT4 = (const float4*)(ws + WS_ATT + (size_t)qi * (NG * LQ));
#pragma unroll
    for (int m = 0; m < 6; ++m) {
        int idx = m * 256 + tid;
        int g = idx >> 7, j4 = idx & 127;
        *(float4*)&atls[g * 516 + j4 * 4] = attT4[g * 128 + j4];
    }
    __syncthreads();

    const int w = tid >> 6, lane = tid & 63, jh = lane >> 5, c4 = lane & 31;
    float acc[NG][4];
#pragma unroll
    for (int g = 0; g < NG; ++g)
#pragma unroll
        for (int r = 0; r < 4; ++r) acc[g][r] = 0.f;
    const float4* e4 = (const float4*)(Edge + (size_t)qi * LQ * CE);
    for (int s = 0; s < 16; ++s) {
        int j0 = w * 128 + jh * 64 + s * 4;
        float4 e0 = e4[(size_t)(j0 + 0) * 32 + c4];
        float4 e1 = e4[(size_t)(j0 + 1) * 32 + c4];
        float4 e2 = e4[(size_t)(j0 + 2) * 32 + c4];
        float4 e3 = e4[(size_t)(j0 + 3) * 32 + c4];
#pragma unroll
        for (int g = 0; g < NG; ++g) {
            float4 a = *(const float4*)&atls[g * 516 + j0];
            acc[g][0] = fmaf(a.x, e0.x, fmaf(a.y, e1.x, fmaf(a.z, e2.x, fmaf(a.w, e3.x, acc[g][0]))));
            acc[g][1] = fmaf(a.x, e0.y, fmaf(a.y, e1.y, fmaf(a.z, e2.y, fmaf(a.w, e3.y, acc[g][1]))));
            acc[g][2] = fmaf(a.x, e0.z, fmaf(a.y, e1.z, fmaf(a.z, e2.z, fmaf(a.w, e3.z, acc[g][2]))));
            acc[g][3] = fmaf(a.x, e0.w, fmaf(a.y, e1.w, fmaf(a.z, e2.w, fmaf(a.w, e3.w, acc[g][3]))));
        }
    }
#pragma unroll
    for (int g = 0; g < NG; ++g)
#pragma unroll
        for (int r = 0; r < 4; ++r) acc[g][r] += __shfl_xor(acc[g][r], 32);
    if (jh == 0) {
#pragma unroll
        for (int g = 0; g < NG; ++g)
#pragma unroll
            for (int r = 0; r < 4; ++r) bufA[w][c4][g][r] = acc[g][r];
    }
    __syncthreads();
    float* feat = ws + WS_FEAT + (size_t)qi * FEAT;
    for (int m = 0; m < 6; ++m) {
        int o = tid + m * 256;
        int g = o >> 7, c = o & 127;
        int cc4 = c >> 2, r = c & 3;
        feat[o] = bufA[0][cc4][g][r] + bufA[1][cc4][g][r] +
                  bufA[2][cc4][g][r] + bufA[3][cc4][g][r];
    }
}

// ---------------- K3b: O_Node / O_vec / O_norm ----------------
__global__ __launch_bounds__(256) void k3b_rest(
    const float* __restrict__ rots, const float* __restrict__ trans,
    float* __restrict__ ws)
{
    __shared__ float atls[NG * 516];
    __shared__ float ovecl[240];
    const int tid = threadIdx.x;
    const int qi = blockIdx.x >> 1;
    const int s  = blockIdx.x & 1;

    const float4* attT4 = (const float4*)(ws + WS_ATT + (size_t)qi * (NG * LQ));
#pragma unroll
    for (int m = 0; m < 6; ++m) {
        int idx = m * 256 + tid;
        int g = idx >> 7, j4 = idx & 127;
        *(float4*)&atls[g * 516 + j4 * 4] = attT4[g * 128 + j4];
    }
    __syncthreads();

    float* feat = ws + WS_FEAT + (size_t)qi * FEAT;
    const float* raw = ws + WS_RAW;
    const float* vvg = ws + WS_VVG;
    if (tid < 240) {
        if (s == 0 && tid < 192) {
            int g = tid >> 4;
            const float* arow = atls + g * 516;
            float sum = 0.f;
            for (int j4 = 0; j4 < 128; ++j4) {
                float4 a = *(const float4*)&arow[j4 * 4];
                int j = j4 * 4;
                sum = fmaf(a.x, raw[(size_t)(j + 0) * NPROJ + 384 + tid], sum);
                sum = fmaf(a.y, raw[(size_t)(j + 1) * NPROJ + 384 + tid], sum);
                sum = fmaf(a.z, raw[(size_t)(j + 2) * NPROJ + 384 + tid], sum);
                sum = fmaf(a.w, raw[(size_t)(j + 3) * NPROJ + 384 + tid], sum);
            }
            feat[1536 + tid] = sum;
        } else {
            int u = (s == 0) ? (tid - 192) : (48 + tid);
            int lidx = (s == 0) ? (tid - 192) : tid;
            int g = u / 24;
            const float* arow = atls + g * 516;
            float sum = 0.f;
            for (int j4 = 0; j4 < 128; ++j4) {
                float4 a = *(const float4*)&arow[j4 * 4];
                int j = j4 * 4;
                sum = fmaf(a.x, vvg[(size_t)(j + 0) * 288 + u], sum);
                sum = fmaf(a.y, vvg[(size_t)(j + 1) * 288 + u], sum);
                sum = fmaf(a.z, vvg[(size_t)(j + 2) * 288 + u], sum);
                sum = fmaf(a.w, vvg[(size_t)(j + 3) * 288 + u], sum);
            }
            ovecl[lidx] = sum;
        }
    }
    __syncthreads();

    int npts = (s == 0) ? 16 : 80;
    if (tid < npts) {
        int P = (s == 0) ? tid : (16 + tid);
        int u0l = (s == 0) ? (P * 3) : (P * 3 - 48);
        const float* R = rots + qi * 9;
        float t0 = trans[qi * 3 + 0] * 0.1f;
        float t1 = trans[qi * 3 + 1] * 0.1f;
        float t2 = trans[qi * 3 + 2] * 0.1f;
        float d0 = ovecl[u0l + 0] - t0;
        float d1 = ovecl[u0l + 1] - t1;
        float d2 = ovecl[u0l + 2] - t2;
        float o0 = R[0] * d0 + R[3] * d1 + R[6] * d2;
        float o1 = R[1] * d0 + R[4] * d1 + R[7] * d2;
        float o2 = R[2] * d0 + R[5] * d1 + R[8] * d2;
        feat[1728 + P * 3 + 0] = o0;
        feat[1728 + P * 3 + 1] = o1;
        feat[1728 + P * 3 + 2] = o2;
        feat[2016 + P] = sqrtf(o0 * o0 + o1 * o1 + o2 * o2 + 1e-8f);
    }
}

// ---------------- K4: feat @ Wout — LDS-tiled GEMM, split-K x3 ----------------
__global__ __launch_bounds__(256) void k4_gemm(const float* __restrict__ Wout,
                                               float* __restrict__ ws)
{
    __shared__ float As[64][68];
    __shared__ float Bs[64][48];
    const int tid = threadIdx.x;
    const int cc = blockIdx.x >> 6;
    const int t  = blockIdx.x & 63;
    const int l0 = (t >> 3) * 64;
    const int col0 = (t & 7) * 48;
    const float* feat = ws + WS_FEAT;

    const int tx = tid & 15, ty = tid >> 4;
    float acc[4][3];
#pragma unroll
    for (int r = 0; r < 4; ++r)
#pragma unroll
        for (int c = 0; c < 3; ++c) acc[r][c] = 0.f;

    for (int kc = cc * 11; kc < cc * 11 + 11; ++kc) {
        __syncthreads();
#pragma unroll
        for (int pass = 0; pass < 4; ++pass) {
            int m = (tid >> 4) + pass * 16;
            int kk = (tid & 15) * 4;
            const float4 a = *(const float4*)(feat + (size_t)(l0 + m) * FEAT + kc * 64 + kk);
            As[kk + 0][m] = a.x; As[kk + 1][m] = a.y;
            As[kk + 2][m] = a.z; As[kk + 3][m] = a.w;
        }
#pragma unroll
        for (int p = 0; p < 12; ++p) {
            int idx = p * 256 + tid;
            int kk = idx / 48, c = idx - kk * 48;
            Bs[kk][c] = Wout[(size_t)(kc * 64 + kk) * CN + col0 + c];
        }
        __syncthreads();
#pragma unroll 8
        for (int kk = 0; kk < 64; ++kk) {
            const float4 av = *(const float4*)&As[kk][tx * 4];
            const float b0 = Bs[kk][ty * 3 + 0];
            const float b1 = Bs[kk][ty * 3 + 1];
            const float b2 = Bs[kk][ty * 3 + 2];
            acc[0][0] = fmaf(av.x, b0, acc[0][0]); acc[0][1] = fmaf(av.x, b1, acc[0][1]); acc[0][2] = fmaf(av.x, b2, acc[0][2]);
            acc[1][0] = fmaf(av.y, b0, acc[1][0]); acc[1][1] = fmaf(av.y, b1, acc[1][1]); acc[1][2] = fmaf(av.y, b2, acc[1][2]);
            acc[2][0] = fmaf(av.z, b0, acc[2][0]); acc[2][1] = fmaf(av.z, b1, acc[2][1]); acc[2][2] = fmaf(av.z, b2, acc[2][2]);
            acc[3][0] = fmaf(av.w, b0, acc[3][0]); acc[3][1] = fmaf(av.w, b1, acc[3][1]); acc[3][2] = fmaf(av.w, b2, acc[3][2]);
        }
    }
    float* part = ws + WS_PART + (size_t)cc * LQ * CN;
#pragma unroll
    for (int r = 0; r < 4; ++r)
#pragma unroll
        for (int c = 0; c < 3; ++c)
            part[(size_t)(l0 + tx * 4 + r) * CN + col0 + ty * 3 + c] = acc[r][c];
}

// ---------------- K5: reduce partials + bias ----------------
__global__ __launch_bounds__(384) void k5_red(const float* __restrict__ bout,
                                              const float* __restrict__ wsc,
                                              float* __restrict__ out)
{
    const int i = blockIdx.x, n = threadIdx.x;
    const float* part = wsc + WS_PART;
    size_t idx = (size_t)i * CN + n;
    size_t st = (size_t)LQ * CN;
    out[idx] = part[idx] + part[st + idx] + part[2 * st + idx] + bout[n];
}

extern "C" void kernel_launch(void* const* d_in, const int* in_sizes, int n_in,
                              void* d_out, int out_size, void* d_ws, size_t ws_size,
                              hipStream_t stream) {
    const float* Node  = (const float*)d_in[0];
    const float* Edge  = (const float*)d_in[1];
    const float* rots  = (const float*)d_in[2];
    const float* trans = (const float*)d_in[3];
    const float* Wq    = (const float*)d_in[4];
    const float* Wk    = (const float*)d_in[5];
    const float* Wv    = (const float*)d_in[6];
    const float* Wqv   = (const float*)d_in[7];
    const float* Wkv   = (const float*)d_in[8];
    const float* Wvv   = (const float*)d_in[9];
    const float* Wbias = (const float*)d_in[10];
    const float* gamma = (const float*)d_in[11];
    const float* Wout  = (const float*)d_in[12];
    const float* bout  = (const float*)d_in[13];
    float* ws = (float*)d_ws;

    k0_wbt<<<6, 256, 0, stream>>>(Wbias, ws);
    k1a_gemm<<<192, 256, 0, stream>>>(Node, Wq, Wk, Wv, Wqv, Wkv, Wvv, ws);
    k1b_vec<<<512, 256, 0, stream>>>(rots, trans, ws);
    k2a_logits<<<1024, 256, 0, stream>>>(gamma, ws);
    k2b_bias<<<512, 256, 0, stream>>>(Edge, ws);
    k3a_oedge<<<512, 256, 0, stream>>>(Edge, ws);
    k3b_rest<<<1024, 256, 0, stream>>>(rots, trans, ws);
    k4_gemm<<<192, 256, 0, stream>>>(Wout, ws);
    k5_red<<<512, 384, 0, stream>>>(bout, ws, (float*)d_out);
}

// Round 14
// 224.977 us; speedup vs baseline: 1.0479x; 1.0479x over previous
//
#include <hip/hip_runtime.h>
#include <math.h>

#define LQ 512
#define CN 384
#define CE 128
#define CH 192
#define NG 12
#define PPG 16
#define FEAT 2112
#define NPROJ 1152
#define WLs 0.5773502691896258f

// ws float offsets
#define WS_RAW  0u         // [l][1152]
#define WS_QVG  589824u    // [l][144]
#define WS_KVT  663552u    // [144][512]
#define WS_VVG  737280u    // [l][288]
#define WS_QN   884736u    // [l][12]
#define WS_KNT  890880u    // [12][512]
#define WS_KT   897024u    // [192][512]
#define WS_ATT  995328u    // [i][12][512] transposed UNNORMALIZED exp
#define WS_FEAT 4141056u   // [i][2112]
#define WS_PART 5222400u   // [3][512][384] (k4/k5 only)
#define WS_WBT  5836800u   // [12][128] transposed Wbias
#define WS_SINV 5838336u   // [i][12] 1/sum
#define WS_LGS  5861376u   // [i][12][512] TRANSPOSED base logits

// ---------------- K0: transpose Wbias -> wbT[12][128] ----------------
__global__ __launch_bounds__(256) void k0_wbt(const float* __restrict__ Wbias,
                                              float* __restrict__ ws)
{
    int idx = blockIdx.x * 256 + threadIdx.x;
    if (idx < CE * NG) {
        int c = idx / NG, g = idx % NG;
        ws[WS_WBT + g * CE + c] = Wbias[idx];
    }
}

// ---------------- K1a: tiled projection GEMM -> raw (+KT transposed copy) ----------------
__global__ __launch_bounds__(256) void k1a_gemm(
    const float* __restrict__ Node,
    const float* __restrict__ Wq, const float* __restrict__ Wk,
    const float* __restrict__ Wv, const float* __restrict__ Wqv,
    const float* __restrict__ Wkv, const float* __restrict__ Wvv,
    float* __restrict__ ws)
{
    __shared__ float As[64][68];
    __shared__ float Bs[64][48];
    const int tid = threadIdx.x;
    const int cb = blockIdx.x % 24;
    const int l0 = (blockIdx.x / 24) * 64;
    const int col0 = cb * 48;

    const float* W; int nc, lc0;
    if (col0 < 192)      { W = Wq;  nc = 192; lc0 = col0; }
    else if (col0 < 384) { W = Wk;  nc = 192; lc0 = col0 - 192; }
    else if (col0 < 576) { W = Wv;  nc = 192; lc0 = col0 - 384; }
    else if (col0 < 720) { W = Wqv; nc = 144; lc0 = col0 - 576; }
    else if (col0 < 864) { W = Wkv; nc = 144; lc0 = col0 - 720; }
    else                 { W = Wvv; nc = 288; lc0 = col0 - 864; }

    const int tx = tid & 15, ty = tid >> 4;
    float acc[4][3];
#pragma unroll
    for (int r = 0; r < 4; ++r)
#pragma unroll
        for (int c = 0; c < 3; ++c) acc[r][c] = 0.f;

    for (int kc = 0; kc < 6; ++kc) {
        __syncthreads();
#pragma unroll
        for (int pass = 0; pass < 4; ++pass) {
            int m = (tid >> 4) + pass * 16;
            int kk = (tid & 15) * 4;
            const float4 a = *(const float4*)(Node + (size_t)(l0 + m) * CN + kc * 64 + kk);
            As[kk + 0][m] = a.x; As[kk + 1][m] = a.y;
            As[kk + 2][m] = a.z; As[kk + 3][m] = a.w;
        }
#pragma unroll
        for (int p = 0; p < 12; ++p) {
            int idx = p * 256 + tid;
            int kk = idx / 48, c = idx - kk * 48;
            Bs[kk][c] = W[(size_t)(kc * 64 + kk) * nc + lc0 + c];
        }
        __syncthreads();
#pragma unroll 8
        for (int kk = 0; kk < 64; ++kk) {
            const float4 av = *(const float4*)&As[kk][tx * 4];
            const float b0 = Bs[kk][ty * 3 + 0];
            const float b1 = Bs[kk][ty * 3 + 1];
            const float b2 = Bs[kk][ty * 3 + 2];
            acc[0][0] = fmaf(av.x, b0, acc[0][0]); acc[0][1] = fmaf(av.x, b1, acc[0][1]); acc[0][2] = fmaf(av.x, b2, acc[0][2]);
            acc[1][0] = fmaf(av.y, b0, acc[1][0]); acc[1][1] = fmaf(av.y, b1, acc[1][1]); acc[1][2] = fmaf(av.y, b2, acc[1][2]);
            acc[2][0] = fmaf(av.z, b0, acc[2][0]); acc[2][1] = fmaf(av.z, b1, acc[2][1]); acc[2][2] = fmaf(av.z, b2, acc[2][2]);
            acc[3][0] = fmaf(av.w, b0, acc[3][0]); acc[3][1] = fmaf(av.w, b1, acc[3][1]); acc[3][2] = fmaf(av.w, b2, acc[3][2]);
        }
    }
    float* raw = ws + WS_RAW;
#pragma unroll
    for (int r = 0; r < 4; ++r)
#pragma unroll
        for (int c = 0; c < 3; ++c)
            raw[(size_t)(l0 + tx * 4 + r) * NPROJ + col0 + ty * 3 + c] = acc[r][c];
    if (col0 >= 192 && col0 < 384) {
#pragma unroll
        for (int r = 0; r < 4; ++r)
#pragma unroll
            for (int c = 0; c < 3; ++c)
                ws[WS_KT + (size_t)(col0 - 192 + ty * 3 + c) * LQ + l0 + tx * 4 + r] = acc[r][c];
    }
}

// ---------------- K1b: frame apply + point norms ----------------
__global__ __launch_bounds__(256) void k1b_vec(
    const float* __restrict__ rots, const float* __restrict__ trans,
    float* __restrict__ ws)
{
    __shared__ float sqbuf[96];
    const int tid = threadIdx.x;
    const int l = blockIdx.x;
    const float* raw = ws + WS_RAW + (size_t)l * NPROJ;

    if (tid < 192) {
        int src, pt, typ;
        if (tid < 48)      { typ = 0; pt = tid;      src = 576 + pt * 3; }
        else if (tid < 96) { typ = 1; pt = tid - 48; src = 720 + pt * 3; }
        else               { typ = 2; pt = tid - 96; src = 864 + pt * 3; }
        float v0 = raw[src], v1 = raw[src + 1], v2 = raw[src + 2];
        const float* R = rots + l * 9;
        float o0 = R[0] * v0 + R[1] * v1 + R[2] * v2 + trans[l * 3 + 0] * 0.1f;
        float o1 = R[3] * v0 + R[4] * v1 + R[5] * v2 + trans[l * 3 + 1] * 0.1f;
        float o2 = R[6] * v0 + R[7] * v1 + R[8] * v2 + trans[l * 3 + 2] * 0.1f;
        if (typ == 0) {
            float* dst = ws + WS_QVG + (size_t)l * 144 + pt * 3;
            dst[0] = o0; dst[1] = o1; dst[2] = o2;
        } else if (typ == 1) {
            ws[WS_KVT + (size_t)(pt * 3 + 0) * LQ + l] = o0;
            ws[WS_KVT + (size_t)(pt * 3 + 1) * LQ + l] = o1;
            ws[WS_KVT + (size_t)(pt * 3 + 2) * LQ + l] = o2;
        } else {
            float* dst = ws + WS_VVG + (size_t)l * 288 + pt * 3;
            dst[0] = o0; dst[1] = o1; dst[2] = o2;
        }
        if (tid < 96) sqbuf[tid] = o0 * o0 + o1 * o1 + o2 * o2;
    }
    __syncthreads();
    if (tid < 24) {
        int typ = tid / 12, g = tid % 12;
        int b = typ * 48 + g * 4;
        float s = sqbuf[b] + sqbuf[b + 1] + sqbuf[b + 2] + sqbuf[b + 3];
        if (typ == 0) ws[WS_QN + (size_t)l * 12 + g] = s;
        else          ws[WS_KNT + (size_t)g * LQ + l] = s;
    }
}

// ---------------- K2a: base logits -> LGS_T (transposed) ----------------
__global__ __launch_bounds__(256) void k2a_logits(
    const float* __restrict__ gamma, float* __restrict__ ws)
{
    __shared__ float cgls[NG];
    const int tid = threadIdx.x;
    const int i = blockIdx.x >> 1;
    const int h = blockIdx.x & 1;
    const int j = h * 256 + tid;

    if (tid < NG)
        cgls[tid] = log1pf(__expf(gamma[tid])) * 0.11785113019775793f;
    __syncthreads();

    const float* qrow  = ws + WS_RAW + (size_t)i * NPROJ;
    const float* qvrow = ws + WS_QVG + (size_t)i * 144;
    const float* qnrow = ws + WS_QN  + (size_t)i * NG;
    const float* KT  = ws + WS_KT;
    const float* KVT = ws + WS_KVT;
    const float* KNT = ws + WS_KNT;
    float* lgsT = ws + WS_LGS + (size_t)i * (NG * LQ);
#pragma unroll
    for (int g = 0; g < NG; ++g) {
        float qk = 0.f;
#pragma unroll
        for (int u = 0; u < PPG; ++u)
            qk = fmaf(qrow[g * PPG + u], KT[(size_t)(g * PPG + u) * LQ + j], qk);
        float dt = 0.f;
#pragma unroll
        for (int u = 0; u < 12; ++u)
            dt = fmaf(qvrow[g * 12 + u], KVT[(size_t)(g * 12 + u) * LQ + j], dt);
        float sq = qnrow[g] + KNT[(size_t)g * LQ + j] - 2.f * dt;
        lgsT[g * LQ + j] = qk * 0.25f - cgls[g] * sq;   // coalesced per g
    }
}

// ---------------- K2f: FUSED single Edge pass: bias + exp(no-max) + O_Edge ----------------
// block = query row i. 16 chunks of 32 rows. No softmax max (logits bounded; R10-validated).
__global__ __launch_bounds__(256, 4) void k2f_fused(
    const float* __restrict__ Edge, float* __restrict__ ws)
{
    __shared__ float et[32 * 132];   // 16.9 KB Edge chunk [row][132] (reused as oeb at end)
    __shared__ float wbs[NG * 132];  // 6.6 KB Wbias transposed, padded
    __shared__ float eT[NG * 68];    // 3.3 KB exp values [g][row]
    __shared__ float sred[32 * 16];  // 2 KB
    __shared__ float sinvl[NG];
    const int tid = threadIdx.x;
    const int i = blockIdx.x;
    const int rA = tid >> 3, qA = tid & 7;     // phase A/B mapping
    const int rh = tid >> 5, c4 = tid & 31;    // phase C mapping

    for (int u = tid; u < NG * CE; u += 256)
        wbs[(u >> 7) * 132 + (u & 127)] = ws[WS_WBT + u];

    float4 acc[NG];
#pragma unroll
    for (int g = 0; g < NG; ++g) { acc[g].x = 0.f; acc[g].y = 0.f; acc[g].z = 0.f; acc[g].w = 0.f; }
    float sloc0 = 0.f, sloc1 = 0.f;

    const float4* e4 = (const float4*)(Edge + (size_t)i * LQ * CE);
    const float* lgsT = ws + WS_LGS + (size_t)i * (NG * LQ);
    float* attT = ws + WS_ATT + (size_t)i * (NG * LQ);

    const int srow = tid >> 5, scc = tid & 31;   // staging coords base (idx = t*256+tid)
    float4 buf[4];
#pragma unroll
    for (int t = 0; t < 4; ++t) {
        int row = t * 8 + srow;                  // (t*256+tid)>>5
        buf[t] = e4[(size_t)row * 32 + scc];
    }

    for (int ch = 0; ch < 16; ++ch) {
#pragma unroll
        for (int t = 0; t < 4; ++t) {
            int row = t * 8 + srow;
            *(float4*)&et[row * 132 + scc * 4] = buf[t];
        }
        __syncthreads();                                   // et ready
        if (ch < 15) {
#pragma unroll
            for (int t = 0; t < 4; ++t) {
                int row = t * 8 + srow;
                buf[t] = e4[(size_t)((ch + 1) * 32 + row) * 32 + scc];
            }
        }
        // Phase A: bias partials (16 channels per thread, all 12 g)
        float part[NG];
#pragma unroll
        for (int g = 0; g < NG; ++g) part[g] = 0.f;
        const float* rowp = et + rA * 132 + qA * 16;
#pragma unroll
        for (int t = 0; t < 4; ++t) {
            float4 ev = *(const float4*)(rowp + t * 4);
#pragma unroll
            for (int g = 0; g < NG; ++g) {
                float4 wv = *(const float4*)&wbs[g * 132 + qA * 16 + t * 4];
                part[g] = fmaf(ev.x, wv.x, fmaf(ev.y, wv.y,
                          fmaf(ev.z, wv.z, fmaf(ev.w, wv.w, part[g]))));
            }
        }
#pragma unroll
        for (int g = 0; g < NG; ++g) {
            part[g] += __shfl_xor(part[g], 1);
            part[g] += __shfl_xor(part[g], 2);
            part[g] += __shfl_xor(part[g], 4);
        }
        // Phase B: exp (no max), write eT + ATT_T, accumulate sums
        if (qA < 6) {
            int j = ch * 32 + rA;
            int g0 = qA * 2;
            float e0 = __expf(WLs * (lgsT[(size_t)g0 * LQ + j] + part[g0]));
            float e1 = __expf(WLs * (lgsT[(size_t)(g0 + 1) * LQ + j] + part[g0 + 1]));
            eT[g0 * 68 + rA] = e0;
            eT[(g0 + 1) * 68 + rA] = e1;
            attT[(size_t)g0 * LQ + j] = e0;
            attT[(size_t)(g0 + 1) * LQ + j] = e1;
            sloc0 += e0;
            sloc1 += e1;
        }
        __syncthreads();                                   // eT ready
        // Phase C: O_Edge accumulation (4 rows per thread)
        {
            const float4* et4 = (const float4*)et;
            int r0 = rh * 4;
            float4 v0 = et4[(r0 + 0) * 33 + c4];
            float4 v1 = et4[(r0 + 1) * 33 + c4];
            float4 v2 = et4[(r0 + 2) * 33 + c4];
            float4 v3 = et4[(r0 + 3) * 33 + c4];
#pragma unroll
            for (int g = 0; g < NG; ++g) {
                float4 w = *(const float4*)&eT[g * 68 + r0];
                acc[g].x = fmaf(w.x, v0.x, fmaf(w.y, v1.x, fmaf(w.z, v2.x, fmaf(w.w, v3.x, acc[g].x))));
                acc[g].y = fmaf(w.x, v0.y, fmaf(w.y, v1.y, fmaf(w.z, v2.y, fmaf(w.w, v3.y, acc[g].y))));
                acc[g].z = fmaf(w.x, v0.z, fmaf(w.y, v1.z, fmaf(w.z, v2.z, fmaf(w.w, v3.z, acc[g].z))));
                acc[g].w = fmaf(w.x, v0.w, fmaf(w.y, v1.w, fmaf(w.z, v2.w, fmaf(w.w, v3.w, acc[g].w))));
            }
        }
        __syncthreads();                                   // et consumed
    }

    // sum reduce -> sinv
    if (qA < 6) {
        sred[rA * 16 + qA * 2 + 0] = sloc0;
        sred[rA * 16 + qA * 2 + 1] = sloc1;
    }
    __syncthreads();
    if (tid < NG) {
        float s = 0.f;
        for (int r = 0; r < 32; ++r) s += sred[r * 16 + tid];
        float inv = 1.f / s;
        sinvl[tid] = inv;
        ws[WS_SINV + (size_t)i * NG + tid] = inv;
    }
    __syncthreads();

    // accumulate per-rh partials into oeb (reuse et)
    float* oeb = et;
    for (int rr = 0; rr < 8; ++rr) {
        if (rh == rr) {
#pragma unroll
            for (int g = 0; g < NG; ++g) {
                float4* d = (float4*)&oeb[g * 132 + c4 * 4];
                if (rr == 0) *d = acc[g];
                else {
                    float4 v = *d;
                    v.x += acc[g].x; v.y += acc[g].y; v.z += acc[g].z; v.w += acc[g].w;
                    *d = v;
                }
            }
        }
        __syncthreads();
    }
    float* feat = ws + WS_FEAT + (size_t)i * FEAT;
#pragma unroll
    for (int m = 0; m < 6; ++m) {
        int o = m * 256 + tid;
        int g = o >> 7, c = o & 127;
        feat[o] = oeb[g * 132 + c] * sinvl[g];
    }
}

// ---------------- K3b: O_Node / O_vec / O_norm (normalizes ATT via sinv) ----------------
__global__ __launch_bounds__(256) void k3b_rest(
    const float* __restrict__ rots, const float* __restrict__ trans,
    float* __restrict__ ws)
{
    __shared__ float atls[NG * 516];
    __shared__ float ovecl[240];
    __shared__ float sinvl[NG];
    const int tid = threadIdx.x;
    const int qi = blockIdx.x >> 1;
    const int s  = blockIdx.x & 1;

    if (tid < NG) sinvl[tid] = ws[WS_SINV + (size_t)qi * NG + tid];
    __syncthreads();

    const float4* attT4 = (const float4*)(ws + WS_ATT + (size_t)qi * (NG * LQ));
#pragma unroll
    for (int m = 0; m < 6; ++m) {
        int idx = m * 256 + tid;
        int g = idx >> 7, j4 = idx & 127;
        float f = sinvl[g];
        float4 v = attT4[g * 128 + j4];
        v.x *= f; v.y *= f; v.z *= f; v.w *= f;
        *(float4*)&atls[g * 516 + j4 * 4] = v;
    }
    __syncthreads();

    float* feat = ws + WS_FEAT + (size_t)qi * FEAT;
    const float* raw = ws + WS_RAW;
    const float* vvg = ws + WS_VVG;
    if (tid < 240) {
        if (s == 0 && tid < 192) {
            int g = tid >> 4;
            const float* arow = atls + g * 516;
            float sum = 0.f;
            for (int j4 = 0; j4 < 128; ++j4) {
                float4 a = *(const float4*)&arow[j4 * 4];
                int j = j4 * 4;
                sum = fmaf(a.x, raw[(size_t)(j + 0) * NPROJ + 384 + tid], sum);
                sum = fmaf(a.y, raw[(size_t)(j + 1) * NPROJ + 384 + tid], sum);
                sum = fmaf(a.z, raw[(size_t)(j + 2) * NPROJ + 384 + tid], sum);
                sum = fmaf(a.w, raw[(size_t)(j + 3) * NPROJ + 384 + tid], sum);
            }
            feat[1536 + tid] = sum;
        } else {
            int u = (s == 0) ? (tid - 192) : (48 + tid);
            int lidx = (s == 0) ? (tid - 192) : tid;
            int g = u / 24;
            const float* arow = atls + g * 516;
            float sum = 0.f;
            for (int j4 = 0; j4 < 128; ++j4) {
                float4 a = *(const float4*)&arow[j4 * 4];
                int j = j4 * 4;
                sum = fmaf(a.x, vvg[(size_t)(j + 0) * 288 + u], sum);
                sum = fmaf(a.y, vvg[(size_t)(j + 1) * 288 + u], sum);
                sum = fmaf(a.z, vvg[(size_t)(j + 2) * 288 + u], sum);
                sum = fmaf(a.w, vvg[(size_t)(j + 3) * 288 + u], sum);
            }
            ovecl[lidx] = sum;
        }
    }
    __syncthreads();

    int npts = (s == 0) ? 16 : 80;
    if (tid < npts) {
        int P = (s == 0) ? tid : (16 + tid);
        int u0l = (s == 0) ? (P * 3) : (P * 3 - 48);
        const float* R = rots + qi * 9;
        float t0 = trans[qi * 3 + 0] * 0.1f;
        float t1 = trans[qi * 3 + 1] * 0.1f;
        float t2 = trans[qi * 3 + 2] * 0.1f;
        float d0 = ovecl[u0l + 0] - t0;
        float d1 = ovecl[u0l + 1] - t1;
        float d2 = ovecl[u0l + 2] - t2;
        float o0 = R[0] * d0 + R[3] * d1 + R[6] * d2;
        float o1 = R[1] * d0 + R[4] * d1 + R[7] * d2;
        float o2 = R[2] * d0 + R[5] * d1 + R[8] * d2;
        feat[1728 + P * 3 + 0] = o0;
        feat[1728 + P * 3 + 1] = o1;
        feat[1728 + P * 3 + 2] = o2;
        feat[2016 + P] = sqrtf(o0 * o0 + o1 * o1 + o2 * o2 + 1e-8f);
    }
}

// ---------------- K4: feat @ Wout — LDS-tiled GEMM, split-K x3 ----------------
__global__ __launch_bounds__(256) void k4_gemm(const float* __restrict__ Wout,
                                               float* __restrict__ ws)
{
    __shared__ float As[64][68];
    __shared__ float Bs[64][48];
    const int tid = threadIdx.x;
    const int cc = blockIdx.x >> 6;
    const int t  = blockIdx.x & 63;
    const int l0 = (t >> 3) * 64;
    const int col0 = (t & 7) * 48;
    const float* feat = ws + WS_FEAT;

    const int tx = tid & 15, ty = tid >> 4;
    float acc[4][3];
#pragma unroll
    for (int r = 0; r < 4; ++r)
#pragma unroll
        for (int c = 0; c < 3; ++c) acc[r][c] = 0.f;

    for (int kc = cc * 11; kc < cc * 11 + 11; ++kc) {
        __syncthreads();
#pragma unroll
        for (int pass = 0; pass < 4; ++pass) {
            int m = (tid >> 4) + pass * 16;
            int kk = (tid & 15) * 4;
            const float4 a = *(const float4*)(feat + (size_t)(l0 + m) * FEAT + kc * 64 + kk);
            As[kk + 0][m] = a.x; As[kk + 1][m] = a.y;
            As[kk + 2][m] = a.z; As[kk + 3][m] = a.w;
        }
#pragma unroll
        for (int p = 0; p < 12; ++p) {
            int idx = p * 256 + tid;
            int kk = idx / 48, c = idx - kk * 48;
            Bs[kk][c] = Wout[(size_t)(kc * 64 + kk) * CN + col0 + c];
        }
        __syncthreads();
#pragma unroll 8
        for (int kk = 0; kk < 64; ++kk) {
            const float4 av = *(const float4*)&As[kk][tx * 4];
            const float b0 = Bs[kk][ty * 3 + 0];
            const float b1 = Bs[kk][ty * 3 + 1];
            const float b2 = Bs[kk][ty * 3 + 2];
            acc[0][0] = fmaf(av.x, b0, acc[0][0]); acc[0][1] = fmaf(av.x, b1, acc[0][1]); acc[0][2] = fmaf(av.x, b2, acc[0][2]);
            acc[1][0] = fmaf(av.y, b0, acc[1][0]); acc[1][1] = fmaf(av.y, b1, acc[1][1]); acc[1][2] = fmaf(av.y, b2, acc[1][2]);
            acc[2][0] = fmaf(av.z, b0, acc[2][0]); acc[2][1] = fmaf(av.z, b1, acc[2][1]); acc[2][2] = fmaf(av.z, b2, acc[2][2]);
            acc[3][0] = fmaf(av.w, b0, acc[3][0]); acc[3][1] = fmaf(av.w, b1, acc[3][1]); acc[3][2] = fmaf(av.w, b2, acc[3][2]);
        }
    }
    float* part = ws + WS_PART + (size_t)cc * LQ * CN;
#pragma unroll
    for (int r = 0; r < 4; ++r)
#pragma unroll
        for (int c = 0; c < 3; ++c)
            part[(size_t)(l0 + tx * 4 + r) * CN + col0 + ty * 3 + c] = acc[r][c];
}

// ---------------- K5: reduce partials + bias ----------------
__global__ __launch_bounds__(384) void k5_red(const float* __restrict__ bout,
                                              const float* __restrict__ wsc,
                                              float* __restrict__ out)
{
    const int i = blockIdx.x, n = threadIdx.x;
    const float* part = wsc + WS_PART;
    size_t idx = (size_t)i * CN + n;
    size_t st = (size_t)LQ * CN;
    out[idx] = part[idx] + part[st + idx] + part[2 * st + idx] + bout[n];
}

extern "C" void kernel_launch(void* const* d_in, const int* in_sizes, int n_in,
                              void* d_out, int out_size, void* d_ws, size_t ws_size,
                              hipStream_t stream) {
    const float* Node  = (const float*)d_in[0];
    const float* Edge  = (const float*)d_in[1];
    const float* rots  = (const float*)d_in[2];
    const float* trans = (const float*)d_in[3];
    const float* Wq    = (const float*)d_in[4];
    const float* Wk    = (const float*)d_in[5];
    const float* Wv    = (const float*)d_in[6];
    const float* Wqv   = (const float*)d_in[7];
    const float* Wkv   = (const float*)d_in[8];
    const float* Wvv   = (const float*)d_in[9];
    const float* Wbias = (const float*)d_in[10];
    const float* gamma = (const float*)d_in[11];
    const float* Wout  = (const float*)d_in[12];
    const float* bout  = (const float*)d_in[13];
    float* ws = (float*)d_ws;

    k0_wbt<<<6, 256, 0, stream>>>(Wbias, ws);
    k1a_gemm<<<192, 256, 0, stream>>>(Node, Wq, Wk, Wv, Wqv, Wkv, Wvv, ws);
    k1b_vec<<<512, 256, 0, stream>>>(rots, trans, ws);
    k2a_logits<<<1024, 256, 0, stream>>>(gamma, ws);
    k2f_fused<<<512, 256, 0, stream>>>(Edge, ws);
    k3b_rest<<<1024, 256, 0, stream>>>(rots, trans, ws);
    k4_gemm<<<192, 256, 0, stream>>>(Wout, ws);
    k5_red<<<512, 384, 0, stream>>>(bout, ws, (float*)d_out);
}

// Round 15
// 190.642 us; speedup vs baseline: 1.2367x; 1.1801x over previous
//
#include <hip/hip_runtime.h>
#include <math.h>

#define LQ 512
#define CN 384
#define CE 128
#define CH 192
#define NG 12
#define PPG 16
#define FEAT 2112
#define NPROJ 1152
#define WLs 0.5773502691896258f

// ws float offsets
#define WS_RAW  0u         // [l][1152]
#define WS_QVG  589824u    // [l][144]
#define WS_KVT  663552u    // [144][512]
#define WS_VVG  737280u    // [l][288]
#define WS_QN   884736u    // [l][12]
#define WS_KNT  890880u    // [12][512]
#define WS_KT   897024u    // [192][512]
#define WS_ATT  995328u    // [i][12][512] transposed unnormalized exp
#define WS_FEAT 4141056u   // [i][2112]
#define WS_PART 5222400u   // [3][512][384] (k4/k5 only)
#define WS_PM   5812224u   // [i][h][12] partial max
#define WS_PS   5824512u   // [i][h][12] partial sum

// ---------------- K1a: tiled projection GEMM -> raw (+KT transposed copy) ----------------
__global__ __launch_bounds__(256) void k1a_gemm(
    const float* __restrict__ Node,
    const float* __restrict__ Wq, const float* __restrict__ Wk,
    const float* __restrict__ Wv, const float* __restrict__ Wqv,
    const float* __restrict__ Wkv, const float* __restrict__ Wvv,
    float* __restrict__ ws)
{
    __shared__ float As[64][68];
    __shared__ float Bs[64][48];
    const int tid = threadIdx.x;
    const int cb = blockIdx.x % 24;
    const int l0 = (blockIdx.x / 24) * 64;
    const int col0 = cb * 48;

    const float* W; int nc, lc0;
    if (col0 < 192)      { W = Wq;  nc = 192; lc0 = col0; }
    else if (col0 < 384) { W = Wk;  nc = 192; lc0 = col0 - 192; }
    else if (col0 < 576) { W = Wv;  nc = 192; lc0 = col0 - 384; }
    else if (col0 < 720) { W = Wqv; nc = 144; lc0 = col0 - 576; }
    else if (col0 < 864) { W = Wkv; nc = 144; lc0 = col0 - 720; }
    else                 { W = Wvv; nc = 288; lc0 = col0 - 864; }

    const int tx = tid & 15, ty = tid >> 4;
    float acc[4][3];
#pragma unroll
    for (int r = 0; r < 4; ++r)
#pragma unroll
        for (int c = 0; c < 3; ++c) acc[r][c] = 0.f;

    for (int kc = 0; kc < 6; ++kc) {
        __syncthreads();
#pragma unroll
        for (int pass = 0; pass < 4; ++pass) {
            int m = (tid >> 4) + pass * 16;
            int kk = (tid & 15) * 4;
            const float4 a = *(const float4*)(Node + (size_t)(l0 + m) * CN + kc * 64 + kk);
            As[kk + 0][m] = a.x; As[kk + 1][m] = a.y;
            As[kk + 2][m] = a.z; As[kk + 3][m] = a.w;
        }
#pragma unroll
        for (int p = 0; p < 12; ++p) {
            int idx = p * 256 + tid;
            int kk = idx / 48, c = idx - kk * 48;
            Bs[kk][c] = W[(size_t)(kc * 64 + kk) * nc + lc0 + c];
        }
        __syncthreads();
#pragma unroll 8
        for (int kk = 0; kk < 64; ++kk) {
            const float4 av = *(const float4*)&As[kk][tx * 4];
            const float b0 = Bs[kk][ty * 3 + 0];
            const float b1 = Bs[kk][ty * 3 + 1];
            const float b2 = Bs[kk][ty * 3 + 2];
            acc[0][0] = fmaf(av.x, b0, acc[0][0]); acc[0][1] = fmaf(av.x, b1, acc[0][1]); acc[0][2] = fmaf(av.x, b2, acc[0][2]);
            acc[1][0] = fmaf(av.y, b0, acc[1][0]); acc[1][1] = fmaf(av.y, b1, acc[1][1]); acc[1][2] = fmaf(av.y, b2, acc[1][2]);
            acc[2][0] = fmaf(av.z, b0, acc[2][0]); acc[2][1] = fmaf(av.z, b1, acc[2][1]); acc[2][2] = fmaf(av.z, b2, acc[2][2]);
            acc[3][0] = fmaf(av.w, b0, acc[3][0]); acc[3][1] = fmaf(av.w, b1, acc[3][1]); acc[3][2] = fmaf(av.w, b2, acc[3][2]);
        }
    }
    float* raw = ws + WS_RAW;
#pragma unroll
    for (int r = 0; r < 4; ++r)
#pragma unroll
        for (int c = 0; c < 3; ++c)
            raw[(size_t)(l0 + tx * 4 + r) * NPROJ + col0 + ty * 3 + c] = acc[r][c];
    if (col0 >= 192 && col0 < 384) {
#pragma unroll
        for (int r = 0; r < 4; ++r)
#pragma unroll
            for (int c = 0; c < 3; ++c)
                ws[WS_KT + (size_t)(col0 - 192 + ty * 3 + c) * LQ + l0 + tx * 4 + r] = acc[r][c];
    }
}

// ---------------- K1b: frame apply + point norms ----------------
__global__ __launch_bounds__(256) void k1b_vec(
    const float* __restrict__ rots, const float* __restrict__ trans,
    float* __restrict__ ws)
{
    __shared__ float sqbuf[96];
    const int tid = threadIdx.x;
    const int l = blockIdx.x;
    const float* raw = ws + WS_RAW + (size_t)l * NPROJ;

    if (tid < 192) {
        int src, pt, typ;
        if (tid < 48)      { typ = 0; pt = tid;      src = 576 + pt * 3; }
        else if (tid < 96) { typ = 1; pt = tid - 48; src = 720 + pt * 3; }
        else               { typ = 2; pt = tid - 96; src = 864 + pt * 3; }
        float v0 = raw[src], v1 = raw[src + 1], v2 = raw[src + 2];
        const float* R = rots + l * 9;
        float o0 = R[0] * v0 + R[1] * v1 + R[2] * v2 + trans[l * 3 + 0] * 0.1f;
        float o1 = R[3] * v0 + R[4] * v1 + R[5] * v2 + trans[l * 3 + 1] * 0.1f;
        float o2 = R[6] * v0 + R[7] * v1 + R[8] * v2 + trans[l * 3 + 2] * 0.1f;
        if (typ == 0) {
            float* dst = ws + WS_QVG + (size_t)l * 144 + pt * 3;
            dst[0] = o0; dst[1] = o1; dst[2] = o2;
        } else if (typ == 1) {
            ws[WS_KVT + (size_t)(pt * 3 + 0) * LQ + l] = o0;
            ws[WS_KVT + (size_t)(pt * 3 + 1) * LQ + l] = o1;
            ws[WS_KVT + (size_t)(pt * 3 + 2) * LQ + l] = o2;
        } else {
            float* dst = ws + WS_VVG + (size_t)l * 288 + pt * 3;
            dst[0] = o0; dst[1] = o1; dst[2] = o2;
        }
        if (tid < 96) sqbuf[tid] = o0 * o0 + o1 * o1 + o2 * o2;
    }
    __syncthreads();
    if (tid < 24) {
        int typ = tid / 12, g = tid % 12;
        int b = typ * 48 + g * 4;
        float s = sqbuf[b] + sqbuf[b + 1] + sqbuf[b + 2] + sqbuf[b + 3];
        if (typ == 0) ws[WS_QN + (size_t)l * 12 + g] = s;
        else          ws[WS_KNT + (size_t)g * LQ + l] = s;
    }
}

// ---------------- K2: logits + bias + partial softmax -> ATT_T (R8-verified structure) ----------------
__global__ __launch_bounds__(256, 4) void k2_attn(
    const float* __restrict__ Edge, const float* __restrict__ Wbias,
    const float* __restrict__ gamma, float* __restrict__ ws)
{
    __shared__ float et[256 * 33];    // 33.8 KB
    __shared__ float cgls[NG];
    __shared__ float red[4][NG];
    const int tid = threadIdx.x;
    const int i = blockIdx.x >> 1;
    const int h = blockIdx.x & 1;
    const int j = h * 256 + tid;

    if (tid < NG)
        cgls[tid] = log1pf(__expf(gamma[tid])) * 0.11785113019775793f; // softplus*WC/2
    __syncthreads();

    // base logits: q.k/4 - cg*sq — q-side uniform (scalar), K-side j-major (coalesced)
    float lgs[NG];
    {
        const float* qrow  = ws + WS_RAW + (size_t)i * NPROJ;
        const float* qvrow = ws + WS_QVG + (size_t)i * 144;
        const float* qnrow = ws + WS_QN  + (size_t)i * NG;
        const float* KT  = ws + WS_KT;
        const float* KVT = ws + WS_KVT;
        const float* KNT = ws + WS_KNT;
#pragma unroll
        for (int g = 0; g < NG; ++g) {
            float qk = 0.f;
#pragma unroll
            for (int u = 0; u < PPG; ++u)
                qk = fmaf(qrow[g * PPG + u], KT[(size_t)(g * PPG + u) * LQ + j], qk);
            float dt = 0.f;
#pragma unroll
            for (int u = 0; u < 12; ++u)
                dt = fmaf(qvrow[g * 12 + u], KVT[(size_t)(g * 12 + u) * LQ + j], dt);
            float sq = qnrow[g] + KNT[(size_t)g * LQ + j] - 2.f * dt;
            lgs[g] = qk * 0.25f - cgls[g] * sq;
        }
    }

    // bias: 4 chunks of 32 channels, Edge LDS-staged; Wbias uniform from global
    const float4* e4 = (const float4*)Edge + ((size_t)i * LQ + h * 256) * 32;
    for (int ch = 0; ch < 4; ++ch) {
        __syncthreads();
#pragma unroll
        for (int kk = 0; kk < 8; ++kk) {
            int idx = kk * 256 + tid;
            int jr = idx >> 3, c4 = idx & 7;
            float4 v = e4[(size_t)jr * 32 + ch * 8 + c4];
            float* d = et + jr * 33 + c4 * 4;
            d[0] = v.x; d[1] = v.y; d[2] = v.z; d[3] = v.w;
        }
        __syncthreads();
        const float* wbch = Wbias + ch * 32 * NG;
        const float* r0 = et + tid * 33;
#pragma unroll 4
        for (int c = 0; c < 32; ++c) {
            float e0 = r0[c];
            const float* wb = wbch + c * NG;
#pragma unroll
            for (int g = 0; g < NG; ++g) lgs[g] = fmaf(e0, wb[g], lgs[g]);
        }
    }

    // partial softmax over this block's 256 keys
    const int wid = tid >> 6, lane = tid & 63;
    float pm[NG];
#pragma unroll
    for (int g = 0; g < NG; ++g) pm[g] = lgs[g];
#pragma unroll
    for (int g = 0; g < NG; ++g)
        for (int off = 1; off < 64; off <<= 1)
            pm[g] = fmaxf(pm[g], __shfl_xor(pm[g], off));
    if (lane == 0) {
#pragma unroll
        for (int g = 0; g < NG; ++g) red[wid][g] = pm[g];
    }
    __syncthreads();
    float gm[NG];
#pragma unroll
    for (int g = 0; g < NG; ++g)
        gm[g] = fmaxf(fmaxf(red[0][g], red[1][g]), fmaxf(red[2][g], red[3][g]));
    if (tid < NG)
        ws[WS_PM + ((size_t)i * 2 + h) * NG + tid] =
            fmaxf(fmaxf(red[0][tid], red[1][tid]), fmaxf(red[2][tid], red[3][tid]));
    __syncthreads();

    float ps[NG];
#pragma unroll
    for (int g = 0; g < NG; ++g) {
        float e = __expf(WLs * (lgs[g] - gm[g]));
        lgs[g] = e;
        ps[g] = e;
    }
#pragma unroll
    for (int g = 0; g < NG; ++g)
        for (int off = 1; off < 64; off <<= 1)
            ps[g] += __shfl_xor(ps[g], off);
    if (lane == 0) {
#pragma unroll
        for (int g = 0; g < NG; ++g) red[wid][g] = ps[g];
    }
    __syncthreads();
    if (tid < NG)
        ws[WS_PS + ((size_t)i * 2 + h) * NG + tid] =
            red[0][tid] + red[1][tid] + red[2][tid] + red[3][tid];

    // store transposed (coalesced per g): ATT_T[i][g][j]
    float* attT = ws + WS_ATT + (size_t)i * (NG * LQ);
#pragma unroll
    for (int g = 0; g < NG; ++g) attT[g * LQ + j] = lgs[g];
}

// ---------------- K3a: O_Edge (single Edge stream, b128 at-reads; R11-verified) ----------------
__global__ __launch_bounds__(256) void k3a_oedge(
    const float* __restrict__ Edge, float* __restrict__ ws)
{
    __shared__ float atls[NG * 516];
    __shared__ float bufA[4][32][NG][4];
    __shared__ float sc[2][NG];
    const int tid = threadIdx.x;
    const int qi = blockIdx.x;

    if (tid < 24) {
        int hh = tid / NG, g = tid % NG;
        float m0 = ws[WS_PM + ((size_t)qi * 2 + 0) * NG + g];
        float m1 = ws[WS_PM + ((size_t)qi * 2 + 1) * NG + g];
        float ss0 = ws[WS_PS + ((size_t)qi * 2 + 0) * NG + g];
        float ss1 = ws[WS_PS + ((size_t)qi * 2 + 1) * NG + g];
        float m = fmaxf(m0, m1);
        float e0 = __expf(WLs * (m0 - m));
        float e1 = __expf(WLs * (m1 - m));
        float denom = ss0 * e0 + ss1 * e1;
        sc[hh][g] = (hh ? e1 : e0) / denom;
    }
    __syncthreads();

    const float4* attT4 = (const float4*)(ws + WS_ATT + (size_t)qi * (NG * LQ));
#pragma unroll
    for (int m = 0; m < 6; ++m) {
        int idx = m * 256 + tid;
        int g = idx >> 7, j4 = idx & 127;
        float s = sc[j4 >> 6][g];
        float4 v = attT4[g * 128 + j4];
        v.x *= s; v.y *= s; v.z *= s; v.w *= s;
        *(float4*)&atls[g * 516 + j4 * 4] = v;
    }
    __syncthreads();

    const int w = tid >> 6, lane = tid & 63, jh = lane >> 5, c4 = lane & 31;
    float acc[NG][4];
#pragma unroll
    for (int g = 0; g < NG; ++g)
#pragma unroll
        for (int r = 0; r < 4; ++r) acc[g][r] = 0.f;
    const float4* e4 = (const float4*)(Edge + (size_t)qi * LQ * CE);
    for (int s = 0; s < 16; ++s) {
        int j0 = w * 128 + jh * 64 + s * 4;
        float4 e0 = e4[(size_t)(j0 + 0) * 32 + c4];
        float4 e1 = e4[(size_t)(j0 + 1) * 32 + c4];
        float4 e2 = e4[(size_t)(j0 + 2) * 32 + c4];
        float4 e3 = e4[(size_t)(j0 + 3) * 32 + c4];
#pragma unroll
        for (int g = 0; g < NG; ++g) {
            float4 a = *(const float4*)&atls[g * 516 + j0];
            acc[g][0] = fmaf(a.x, e0.x, fmaf(a.y, e1.x, fmaf(a.z, e2.x, fmaf(a.w, e3.x, acc[g][0]))));
            acc[g][1] = fmaf(a.x, e0.y, fmaf(a.y, e1.y, fmaf(a.z, e2.y, fmaf(a.w, e3.y, acc[g][1]))));
            acc[g][2] = fmaf(a.x, e0.z, fmaf(a.y, e1.z, fmaf(a.z, e2.z, fmaf(a.w, e3.z, acc[g][2]))));
            acc[g][3] = fmaf(a.x, e0.w, fmaf(a.y, e1.w, fmaf(a.z, e2.w, fmaf(a.w, e3.w, acc[g][3]))));
        }
    }
#pragma unroll
    for (int g = 0; g < NG; ++g)
#pragma unroll
        for (int r = 0; r < 4; ++r) acc[g][r] += __shfl_xor(acc[g][r], 32);
    if (jh == 0) {
#pragma unroll
        for (int g = 0; g < NG; ++g)
#pragma unroll
            for (int r = 0; r < 4; ++r) bufA[w][c4][g][r] = acc[g][r];
    }
    __syncthreads();
    float* feat = ws + WS_FEAT + (size_t)qi * FEAT;
    for (int m = 0; m < 6; ++m) {
        int o = tid + m * 256;
        int g = o >> 7, c = o & 127;
        int cc4 = c >> 2, r = c & 3;
        feat[o] = bufA[0][cc4][g][r] + bufA[1][cc4][g][r] +
                  bufA[2][cc4][g][r] + bufA[3][cc4][g][r];
    }
}

// ---------------- K3b: O_Node / O_vec / O_norm (R11-verified) ----------------
__global__ __launch_bounds__(256) void k3b_rest(
    const float* __restrict__ rots, const float* __restrict__ trans,
    float* __restrict__ ws)
{
    __shared__ float atls[NG * 516];
    __shared__ float sc[2][NG];
    __shared__ float ovecl[240];
    const int tid = threadIdx.x;
    const int qi = blockIdx.x >> 1;
    const int s  = blockIdx.x & 1;

    if (tid < 24) {
        int hh = tid / NG, g = tid % NG;
        float m0 = ws[WS_PM + ((size_t)qi * 2 + 0) * NG + g];
        float m1 = ws[WS_PM + ((size_t)qi * 2 + 1) * NG + g];
        float ss0 = ws[WS_PS + ((size_t)qi * 2 + 0) * NG + g];
        float ss1 = ws[WS_PS + ((size_t)qi * 2 + 1) * NG + g];
        float m = fmaxf(m0, m1);
        float e0 = __expf(WLs * (m0 - m));
        float e1 = __expf(WLs * (m1 - m));
        float denom = ss0 * e0 + ss1 * e1;
        sc[hh][g] = (hh ? e1 : e0) / denom;
    }
    __syncthreads();

    const float4* attT4 = (const float4*)(ws + WS_ATT + (size_t)qi * (NG * LQ));
#pragma unroll
    for (int m = 0; m < 6; ++m) {
        int idx = m * 256 + tid;
        int g = idx >> 7, j4 = idx & 127;
        float f = sc[j4 >> 6][g];
        float4 v = attT4[g * 128 + j4];
        v.x *= f; v.y *= f; v.z *= f; v.w *= f;
        *(float4*)&atls[g * 516 + j4 * 4] = v;
    }
    __syncthreads();

    float* feat = ws + WS_FEAT + (size_t)qi * FEAT;
    const float* raw = ws + WS_RAW;
    const float* vvg = ws + WS_VVG;
    if (tid < 240) {
        if (s == 0 && tid < 192) {
            int g = tid >> 4;
            const float* arow = atls + g * 516;
            float sum = 0.f;
            for (int j4 = 0; j4 < 128; ++j4) {
                float4 a = *(const float4*)&arow[j4 * 4];
                int j = j4 * 4;
                sum = fmaf(a.x, raw[(size_t)(j + 0) * NPROJ + 384 + tid], sum);
                sum = fmaf(a.y, raw[(size_t)(j + 1) * NPROJ + 384 + tid], sum);
                sum = fmaf(a.z, raw[(size_t)(j + 2) * NPROJ + 384 + tid], sum);
                sum = fmaf(a.w, raw[(size_t)(j + 3) * NPROJ + 384 + tid], sum);
            }
            feat[1536 + tid] = sum;
        } else {
            int u = (s == 0) ? (tid - 192) : (48 + tid);
            int lidx = (s == 0) ? (tid - 192) : tid;
            int g = u / 24;
            const float* arow = atls + g * 516;
            float sum = 0.f;
            for (int j4 = 0; j4 < 128; ++j4) {
                float4 a = *(const float4*)&arow[j4 * 4];
                int j = j4 * 4;
                sum = fmaf(a.x, vvg[(size_t)(j + 0) * 288 + u], sum);
                sum = fmaf(a.y, vvg[(size_t)(j + 1) * 288 + u], sum);
                sum = fmaf(a.z, vvg[(size_t)(j + 2) * 288 + u], sum);
                sum = fmaf(a.w, vvg[(size_t)(j + 3) * 288 + u], sum);
            }
            ovecl[lidx] = sum;
        }
    }
    __syncthreads();

    int npts = (s == 0) ? 16 : 80;
    if (tid < npts) {
        int P = (s == 0) ? tid : (16 + tid);
        int u0l = (s == 0) ? (P * 3) : (P * 3 - 48);
        const float* R = rots + qi * 9;
        float t0 = trans[qi * 3 + 0] * 0.1f;
        float t1 = trans[qi * 3 + 1] * 0.1f;
        float t2 = trans[qi * 3 + 2] * 0.1f;
        float d0 = ovecl[u0l + 0] - t0;
        float d1 = ovecl[u0l + 1] - t1;
        float d2 = ovecl[u0l + 2] - t2;
        float o0 = R[0] * d0 + R[3] * d1 + R[6] * d2;
        float o1 = R[1] * d0 + R[4] * d1 + R[7] * d2;
        float o2 = R[2] * d0 + R[5] * d1 + R[8] * d2;
        feat[1728 + P * 3 + 0] = o0;
        feat[1728 + P * 3 + 1] = o1;
        feat[1728 + P * 3 + 2] = o2;
        feat[2016 + P] = sqrtf(o0 * o0 + o1 * o1 + o2 * o2 + 1e-8f);
    }
}

// ---------------- K4: feat @ Wout — LDS-tiled GEMM, split-K x3 ----------------
__global__ __launch_bounds__(256) void k4_gemm(const float* __restrict__ Wout,
                                               float* __restrict__ ws)
{
    __shared__ float As[64][68];
    __shared__ float Bs[64][48];
    const int tid = threadIdx.x;
    const int cc = blockIdx.x >> 6;
    const int t  = blockIdx.x & 63;
    const int l0 = (t >> 3) * 64;
    const int col0 = (t & 7) * 48;
    const float* feat = ws + WS_FEAT;

    const int tx = tid & 15, ty = tid >> 4;
    float acc[4][3];
#pragma unroll
    for (int r = 0; r < 4; ++r)
#pragma unroll
        for (int c = 0; c < 3; ++c) acc[r][c] = 0.f;

    for (int kc = cc * 11; kc < cc * 11 + 11; ++kc) {
        __syncthreads();
#pragma unroll
        for (int pass = 0; pass < 4; ++pass) {
            int m = (tid >> 4) + pass * 16;
            int kk = (tid & 15) * 4;
            const float4 a = *(const float4*)(feat + (size_t)(l0 + m) * FEAT + kc * 64 + kk);
            As[kk + 0][m] = a.x; As[kk + 1][m] = a.y;
            As[kk + 2][m] = a.z; As[kk + 3][m] = a.w;
        }
#pragma unroll
        for (int p = 0; p < 12; ++p) {
            int idx = p * 256 + tid;
            int kk = idx / 48, c = idx - kk * 48;
            Bs[kk][c] = Wout[(size_t)(kc * 64 + kk) * CN + col0 + c];
        }
        __syncthreads();
#pragma unroll 8
        for (int kk = 0; kk < 64; ++kk) {
            const float4 av = *(const float4*)&As[kk][tx * 4];
            const float b0 = Bs[kk][ty * 3 + 0];
            const float b1 = Bs[kk][ty * 3 + 1];
            const float b2 = Bs[kk][ty * 3 + 2];
            acc[0][0] = fmaf(av.x, b0, acc[0][0]); acc[0][1] = fmaf(av.x, b1, acc[0][1]); acc[0][2] = fmaf(av.x, b2, acc[0][2]);
            acc[1][0] = fmaf(av.y, b0, acc[1][0]); acc[1][1] = fmaf(av.y, b1, acc[1][1]); acc[1][2] = fmaf(av.y, b2, acc[1][2]);
            acc[2][0] = fmaf(av.z, b0, acc[2][0]); acc[2][1] = fmaf(av.z, b1, acc[2][1]); acc[2][2] = fmaf(av.z, b2, acc[2][2]);
            acc[3][0] = fmaf(av.w, b0, acc[3][0]); acc[3][1] = fmaf(av.w, b1, acc[3][1]); acc[3][2] = fmaf(av.w, b2, acc[3][2]);
        }
    }
    float* part = ws + WS_PART + (size_t)cc * LQ * CN;
#pragma unroll
    for (int r = 0; r < 4; ++r)
#pragma unroll
        for (int c = 0; c < 3; ++c)
            part[(size_t)(l0 + tx * 4 + r) * CN + col0 + ty * 3 + c] = acc[r][c];
}

// ---------------- K5: reduce partials + bias ----------------
__global__ __launch_bounds__(384) void k5_red(const float* __restrict__ bout,
                                              const float* __restrict__ wsc,
                                              float* __restrict__ out)
{
    const int i = blockIdx.x, n = threadIdx.x;
    const float* part = wsc + WS_PART;
    size_t idx = (size_t)i * CN + n;
    size_t st = (size_t)LQ * CN;
    out[idx] = part[idx] + part[st + idx] + part[2 * st + idx] + bout[n];
}

extern "C" void kernel_launch(void* const* d_in, const int* in_sizes, int n_in,
                              void* d_out, int out_size, void* d_ws, size_t ws_size,
                              hipStream_t stream) {
    const float* Node  = (const float*)d_in[0];
    const float* Edge  = (const float*)d_in[1];
    const float* rots  = (const float*)d_in[2];
    const float* trans = (const float*)d_in[3];
    const float* Wq    = (const float*)d_in[4];
    const float* Wk    = (const float*)d_in[5];
    const float* Wv    = (const float*)d_in[6];
    const float* Wqv   = (const float*)d_in[7];
    const float* Wkv   = (const float*)d_in[8];
    const float* Wvv   = (const float*)d_in[9];
    const float* Wbias = (const float*)d_in[10];
    const float* gamma = (const float*)d_in[11];
    const float* Wout  = (const float*)d_in[12];
    const float* bout  = (const float*)d_in[13];
    float* ws = (float*)d_ws;

    k1a_gemm<<<192, 256, 0, stream>>>(Node, Wq, Wk, Wv, Wqv, Wkv, Wvv, ws);
    k1b_vec<<<512, 256, 0, stream>>>(rots, trans, ws);
    k2_attn<<<1024, 256, 0, stream>>>(Edge, Wbias, gamma, ws);
    k3a_oedge<<<512, 256, 0, stream>>>(Edge, ws);
    k3b_rest<<<1024, 256, 0, stream>>>(rots, trans, ws);
    k4_gemm<<<192, 256, 0, stream>>>(Wout, ws);
    k5_red<<<512, 384, 0, stream>>>(bout, ws, (float*)d_out);
}

// Round 16
// 189.633 us; speedup vs baseline: 1.2433x; 1.0053x over previous
//
#include <hip/hip_runtime.h>
#include <math.h>

#define LQ 512
#define CN 384
#define CE 128
#define CH 192
#define NG 12
#define PPG 16
#define FEAT 2112
#define NPROJ 1152
#define WLs 0.5773502691896258f

// ws float offsets
#define WS_RAW  0u         // [l][1152]
#define WS_QVG  589824u    // [l][144]
#define WS_KVT  663552u    // [144][512]
#define WS_VVG  737280u    // [l][288]
#define WS_QN   884736u    // [l][12]
#define WS_KNT  890880u    // [12][512]
#define WS_KT   897024u    // [192][512]
#define WS_ATT  995328u    // [i][12][512] transposed unnormalized exp
#define WS_FEAT 4141056u   // [i][2112]
#define WS_PART 5222400u   // [3][512][384] (k4/k5 only)
#define WS_PM   5812224u   // [i][h][12] partial max
#define WS_PS   5824512u   // [i][h][12] partial sum

// ---------------- K1a: tiled projection GEMM -> raw (+KT transposed copy) ----------------
__global__ __launch_bounds__(256) void k1a_gemm(
    const float* __restrict__ Node,
    const float* __restrict__ Wq, const float* __restrict__ Wk,
    const float* __restrict__ Wv, const float* __restrict__ Wqv,
    const float* __restrict__ Wkv, const float* __restrict__ Wvv,
    float* __restrict__ ws)
{
    __shared__ float As[64][68];
    __shared__ float Bs[64][48];
    const int tid = threadIdx.x;
    const int cb = blockIdx.x % 24;
    const int l0 = (blockIdx.x / 24) * 64;
    const int col0 = cb * 48;

    const float* W; int nc, lc0;
    if (col0 < 192)      { W = Wq;  nc = 192; lc0 = col0; }
    else if (col0 < 384) { W = Wk;  nc = 192; lc0 = col0 - 192; }
    else if (col0 < 576) { W = Wv;  nc = 192; lc0 = col0 - 384; }
    else if (col0 < 720) { W = Wqv; nc = 144; lc0 = col0 - 576; }
    else if (col0 < 864) { W = Wkv; nc = 144; lc0 = col0 - 720; }
    else                 { W = Wvv; nc = 288; lc0 = col0 - 864; }

    const int tx = tid & 15, ty = tid >> 4;
    float acc[4][3];
#pragma unroll
    for (int r = 0; r < 4; ++r)
#pragma unroll
        for (int c = 0; c < 3; ++c) acc[r][c] = 0.f;

    for (int kc = 0; kc < 6; ++kc) {
        __syncthreads();
#pragma unroll
        for (int pass = 0; pass < 4; ++pass) {
            int m = (tid >> 4) + pass * 16;
            int kk = (tid & 15) * 4;
            const float4 a = *(const float4*)(Node + (size_t)(l0 + m) * CN + kc * 64 + kk);
            As[kk + 0][m] = a.x; As[kk + 1][m] = a.y;
            As[kk + 2][m] = a.z; As[kk + 3][m] = a.w;
        }
#pragma unroll
        for (int p = 0; p < 12; ++p) {
            int idx = p * 256 + tid;
            int kk = idx / 48, c = idx - kk * 48;
            Bs[kk][c] = W[(size_t)(kc * 64 + kk) * nc + lc0 + c];
        }
        __syncthreads();
#pragma unroll 8
        for (int kk = 0; kk < 64; ++kk) {
            const float4 av = *(const float4*)&As[kk][tx * 4];
            const float b0 = Bs[kk][ty * 3 + 0];
            const float b1 = Bs[kk][ty * 3 + 1];
            const float b2 = Bs[kk][ty * 3 + 2];
            acc[0][0] = fmaf(av.x, b0, acc[0][0]); acc[0][1] = fmaf(av.x, b1, acc[0][1]); acc[0][2] = fmaf(av.x, b2, acc[0][2]);
            acc[1][0] = fmaf(av.y, b0, acc[1][0]); acc[1][1] = fmaf(av.y, b1, acc[1][1]); acc[1][2] = fmaf(av.y, b2, acc[1][2]);
            acc[2][0] = fmaf(av.z, b0, acc[2][0]); acc[2][1] = fmaf(av.z, b1, acc[2][1]); acc[2][2] = fmaf(av.z, b2, acc[2][2]);
            acc[3][0] = fmaf(av.w, b0, acc[3][0]); acc[3][1] = fmaf(av.w, b1, acc[3][1]); acc[3][2] = fmaf(av.w, b2, acc[3][2]);
        }
    }
    float* raw = ws + WS_RAW;
#pragma unroll
    for (int r = 0; r < 4; ++r)
#pragma unroll
        for (int c = 0; c < 3; ++c)
            raw[(size_t)(l0 + tx * 4 + r) * NPROJ + col0 + ty * 3 + c] = acc[r][c];
    if (col0 >= 192 && col0 < 384) {
#pragma unroll
        for (int r = 0; r < 4; ++r)
#pragma unroll
            for (int c = 0; c < 3; ++c)
                ws[WS_KT + (size_t)(col0 - 192 + ty * 3 + c) * LQ + l0 + tx * 4 + r] = acc[r][c];
    }
}

// ---------------- K1b: frame apply + point norms ----------------
__global__ __launch_bounds__(256) void k1b_vec(
    const float* __restrict__ rots, const float* __restrict__ trans,
    float* __restrict__ ws)
{
    __shared__ float sqbuf[96];
    const int tid = threadIdx.x;
    const int l = blockIdx.x;
    const float* raw = ws + WS_RAW + (size_t)l * NPROJ;

    if (tid < 192) {
        int src, pt, typ;
        if (tid < 48)      { typ = 0; pt = tid;      src = 576 + pt * 3; }
        else if (tid < 96) { typ = 1; pt = tid - 48; src = 720 + pt * 3; }
        else               { typ = 2; pt = tid - 96; src = 864 + pt * 3; }
        float v0 = raw[src], v1 = raw[src + 1], v2 = raw[src + 2];
        const float* R = rots + l * 9;
        float o0 = R[0] * v0 + R[1] * v1 + R[2] * v2 + trans[l * 3 + 0] * 0.1f;
        float o1 = R[3] * v0 + R[4] * v1 + R[5] * v2 + trans[l * 3 + 1] * 0.1f;
        float o2 = R[6] * v0 + R[7] * v1 + R[8] * v2 + trans[l * 3 + 2] * 0.1f;
        if (typ == 0) {
            float* dst = ws + WS_QVG + (size_t)l * 144 + pt * 3;
            dst[0] = o0; dst[1] = o1; dst[2] = o2;
        } else if (typ == 1) {
            ws[WS_KVT + (size_t)(pt * 3 + 0) * LQ + l] = o0;
            ws[WS_KVT + (size_t)(pt * 3 + 1) * LQ + l] = o1;
            ws[WS_KVT + (size_t)(pt * 3 + 2) * LQ + l] = o2;
        } else {
            float* dst = ws + WS_VVG + (size_t)l * 288 + pt * 3;
            dst[0] = o0; dst[1] = o1; dst[2] = o2;
        }
        if (tid < 96) sqbuf[tid] = o0 * o0 + o1 * o1 + o2 * o2;
    }
    __syncthreads();
    if (tid < 24) {
        int typ = tid / 12, g = tid % 12;
        int b = typ * 48 + g * 4;
        float s = sqbuf[b] + sqbuf[b + 1] + sqbuf[b + 2] + sqbuf[b + 3];
        if (typ == 0) ws[WS_QN + (size_t)l * 12 + g] = s;
        else          ws[WS_KNT + (size_t)g * LQ + l] = s;
    }
}

// ---------------- K2: logits + bias + partial softmax -> ATT_T ----------------
// R15 structure + T14 async-stage: loads for chunk ch+1 issued before compute of ch.
__global__ __launch_bounds__(256, 4) void k2_attn(
    const float* __restrict__ Edge, const float* __restrict__ Wbias,
    const float* __restrict__ gamma, float* __restrict__ ws)
{
    __shared__ float et[256 * 33];    // 33.8 KB single buffer
    __shared__ float cgls[NG];
    __shared__ float red[4][NG];
    const int tid = threadIdx.x;
    const int i = blockIdx.x >> 1;
    const int h = blockIdx.x & 1;
    const int j = h * 256 + tid;

    if (tid < NG)
        cgls[tid] = log1pf(__expf(gamma[tid])) * 0.11785113019775793f; // softplus*WC/2

    // issue chunk 0 loads FIRST (latency hides under the logits phase)
    const float4* e4 = (const float4*)Edge + ((size_t)i * LQ + h * 256) * 32;
    float4 buf[8];
#pragma unroll
    for (int kk = 0; kk < 8; ++kk) {
        int idx = kk * 256 + tid;
        buf[kk] = e4[(size_t)(idx >> 3) * 32 + (idx & 7)];
    }
    __syncthreads();   // cgls visible

    // base logits: q.k/4 - cg*sq — q-side uniform (scalar), K-side j-major (coalesced)
    float lgs[NG];
    {
        const float* qrow  = ws + WS_RAW + (size_t)i * NPROJ;
        const float* qvrow = ws + WS_QVG + (size_t)i * 144;
        const float* qnrow = ws + WS_QN  + (size_t)i * NG;
        const float* KT  = ws + WS_KT;
        const float* KVT = ws + WS_KVT;
        const float* KNT = ws + WS_KNT;
#pragma unroll
        for (int g = 0; g < NG; ++g) {
            float qk = 0.f;
#pragma unroll
            for (int u = 0; u < PPG; ++u)
                qk = fmaf(qrow[g * PPG + u], KT[(size_t)(g * PPG + u) * LQ + j], qk);
            float dt = 0.f;
#pragma unroll
            for (int u = 0; u < 12; ++u)
                dt = fmaf(qvrow[g * 12 + u], KVT[(size_t)(g * 12 + u) * LQ + j], dt);
            float sq = qnrow[g] + KNT[(size_t)g * LQ + j] - 2.f * dt;
            lgs[g] = qk * 0.25f - cgls[g] * sq;
        }
    }

    // write chunk 0 to LDS
#pragma unroll
    for (int kk = 0; kk < 8; ++kk) {
        int idx = kk * 256 + tid;
        float* d = et + (idx >> 3) * 33 + (idx & 7) * 4;
        d[0] = buf[kk].x; d[1] = buf[kk].y; d[2] = buf[kk].z; d[3] = buf[kk].w;
    }
    __syncthreads();

    for (int ch = 0; ch < 4; ++ch) {
        // issue chunk ch+1's loads BEFORE computing chunk ch (T14)
        if (ch < 3) {
#pragma unroll
            for (int kk = 0; kk < 8; ++kk) {
                int idx = kk * 256 + tid;
                buf[kk] = e4[(size_t)(idx >> 3) * 32 + (ch + 1) * 8 + (idx & 7)];
            }
        }
        const float* wbch = Wbias + ch * 32 * NG;   // uniform -> s_load
        const float* r0 = et + tid * 33;
#pragma unroll 4
        for (int c = 0; c < 32; ++c) {
            float e0 = r0[c];
            const float* wb = wbch + c * NG;
#pragma unroll
            for (int g = 0; g < NG; ++g) lgs[g] = fmaf(e0, wb[g], lgs[g]);
        }
        __syncthreads();       // all reads of et done
        if (ch < 3) {
#pragma unroll
            for (int kk = 0; kk < 8; ++kk) {
                int idx = kk * 256 + tid;
                float* d = et + (idx >> 3) * 33 + (idx & 7) * 4;
                d[0] = buf[kk].x; d[1] = buf[kk].y; d[2] = buf[kk].z; d[3] = buf[kk].w;
            }
            __syncthreads();   // et ready for next chunk
        }
    }

    // partial softmax over this block's 256 keys
    const int wid = tid >> 6, lane = tid & 63;
    float pm[NG];
#pragma unroll
    for (int g = 0; g < NG; ++g) pm[g] = lgs[g];
#pragma unroll
    for (int g = 0; g < NG; ++g)
        for (int off = 1; off < 64; off <<= 1)
            pm[g] = fmaxf(pm[g], __shfl_xor(pm[g], off));
    if (lane == 0) {
#pragma unroll
        for (int g = 0; g < NG; ++g) red[wid][g] = pm[g];
    }
    __syncthreads();
    float gm[NG];
#pragma unroll
    for (int g = 0; g < NG; ++g)
        gm[g] = fmaxf(fmaxf(red[0][g], red[1][g]), fmaxf(red[2][g], red[3][g]));
    if (tid < NG)
        ws[WS_PM + ((size_t)i * 2 + h) * NG + tid] =
            fmaxf(fmaxf(red[0][tid], red[1][tid]), fmaxf(red[2][tid], red[3][tid]));
    __syncthreads();

    float ps[NG];
#pragma unroll
    for (int g = 0; g < NG; ++g) {
        float e = __expf(WLs * (lgs[g] - gm[g]));
        lgs[g] = e;
        ps[g] = e;
    }
#pragma unroll
    for (int g = 0; g < NG; ++g)
        for (int off = 1; off < 64; off <<= 1)
            ps[g] += __shfl_xor(ps[g], off);
    if (lane == 0) {
#pragma unroll
        for (int g = 0; g < NG; ++g) red[wid][g] = ps[g];
    }
    __syncthreads();
    if (tid < NG)
        ws[WS_PS + ((size_t)i * 2 + h) * NG + tid] =
            red[0][tid] + red[1][tid] + red[2][tid] + red[3][tid];

    // store transposed (coalesced per g): ATT_T[i][g][j]
    float* attT = ws + WS_ATT + (size_t)i * (NG * LQ);
#pragma unroll
    for (int g = 0; g < NG; ++g) attT[g * LQ + j] = lgs[g];
}

// ---------------- K3a: O_Edge (single Edge stream, b128 at-reads) ----------------
__global__ __launch_bounds__(256) void k3a_oedge(
    const float* __restrict__ Edge, float* __restrict__ ws)
{
    __shared__ float atls[NG * 516];
    __shared__ float bufA[4][32][NG][4];
    __shared__ float sc[2][NG];
    const int tid = threadIdx.x;
    const int qi = blockIdx.x;

    if (tid < 24) {
        int hh = tid / NG, g = tid % NG;
        float m0 = ws[WS_PM + ((size_t)qi * 2 + 0) * NG + g];
        float m1 = ws[WS_PM + ((size_t)qi * 2 + 1) * NG + g];
        float ss0 = ws[WS_PS + ((size_t)qi * 2 + 0) * NG + g];
        float ss1 = ws[WS_PS + ((size_t)qi * 2 + 1) * NG + g];
        float m = fmaxf(m0, m1);
        float e0 = __expf(WLs * (m0 - m));
        float e1 = __expf(WLs * (m1 - m));
        float denom = ss0 * e0 + ss1 * e1;
        sc[hh][g] = (hh ? e1 : e0) / denom;
    }
    __syncthreads();

    const float4* attT4 = (const float4*)(ws + WS_ATT + (size_t)qi * (NG * LQ));
#pragma unroll
    for (int m = 0; m < 6; ++m) {
        int idx = m * 256 + tid;
        int g = idx >> 7, j4 = idx & 127;
        float s = sc[j4 >> 6][g];
        float4 v = attT4[g * 128 + j4];
        v.x *= s; v.y *= s; v.z *= s; v.w *= s;
        *(float4*)&atls[g * 516 + j4 * 4] = v;
    }
    __syncthreads();

    const int w = tid >> 6, lane = tid & 63, jh = lane >> 5, c4 = lane & 31;
    float acc[NG][4];
#pragma unroll
    for (int g = 0; g < NG; ++g)
#pragma unroll
        for (int r = 0; r < 4; ++r) acc[g][r] = 0.f;
    const float4* e4 = (const float4*)(Edge + (size_t)qi * LQ * CE);
    for (int s = 0; s < 16; ++s) {
        int j0 = w * 128 + jh * 64 + s * 4;
        float4 e0 = e4[(size_t)(j0 + 0) * 32 + c4];
        float4 e1 = e4[(size_t)(j0 + 1) * 32 + c4];
        float4 e2 = e4[(size_t)(j0 + 2) * 32 + c4];
        float4 e3 = e4[(size_t)(j0 + 3) * 32 + c4];
#pragma unroll
        for (int g = 0; g < NG; ++g) {
            float4 a = *(const float4*)&atls[g * 516 + j0];
            acc[g][0] = fmaf(a.x, e0.x, fmaf(a.y, e1.x, fmaf(a.z, e2.x, fmaf(a.w, e3.x, acc[g][0]))));
            acc[g][1] = fmaf(a.x, e0.y, fmaf(a.y, e1.y, fmaf(a.z, e2.y, fmaf(a.w, e3.y, acc[g][1]))));
            acc[g][2] = fmaf(a.x, e0.z, fmaf(a.y, e1.z, fmaf(a.z, e2.z, fmaf(a.w, e3.z, acc[g][2]))));
            acc[g][3] = fmaf(a.x, e0.w, fmaf(a.y, e1.w, fmaf(a.z, e2.w, fmaf(a.w, e3.w, acc[g][3]))));
        }
    }
#pragma unroll
    for (int g = 0; g < NG; ++g)
#pragma unroll
        for (int r = 0; r < 4; ++r) acc[g][r] += __shfl_xor(acc[g][r], 32);
    if (jh == 0) {
#pragma unroll
        for (int g = 0; g < NG; ++g)
#pragma unroll
            for (int r = 0; r < 4; ++r) bufA[w][c4][g][r] = acc[g][r];
    }
    __syncthreads();
    float* feat = ws + WS_FEAT + (size_t)qi * FEAT;
    for (int m = 0; m < 6; ++m) {
        int o = tid + m * 256;
        int g = o >> 7, c = o & 127;
        int cc4 = c >> 2, r = c & 3;
        feat[o] = bufA[0][cc4][g][r] + bufA[1][cc4][g][r] +
                  bufA[2][cc4][g][r] + bufA[3][cc4][g][r];
    }
}

// ---------------- K3b: O_Node / O_vec / O_norm ----------------
__global__ __launch_bounds__(256) void k3b_rest(
    const float* __restrict__ rots, const float* __restrict__ trans,
    float* __restrict__ ws)
{
    __shared__ float atls[NG * 516];
    __shared__ float sc[2][NG];
    __shared__ float ovecl[240];
    const int tid = threadIdx.x;
    const int qi = blockIdx.x >> 1;
    const int s  = blockIdx.x & 1;

    if (tid < 24) {
        int hh = tid / NG, g = tid % NG;
        float m0 = ws[WS_PM + ((size_t)qi * 2 + 0) * NG + g];
        float m1 = ws[WS_PM + ((size_t)qi * 2 + 1) * NG + g];
        float ss0 = ws[WS_PS + ((size_t)qi * 2 + 0) * NG + g];
        float ss1 = ws[WS_PS + ((size_t)qi * 2 + 1) * NG + g];
        float m = fmaxf(m0, m1);
        float e0 = __expf(WLs * (m0 - m));
        float e1 = __expf(WLs * (m1 - m));
        float denom = ss0 * e0 + ss1 * e1;
        sc[hh][g] = (hh ? e1 : e0) / denom;
    }
    __syncthreads();

    const float4* attT4 = (const float4*)(ws + WS_ATT + (size_t)qi * (NG * LQ));
#pragma unroll
    for (int m = 0; m < 6; ++m) {
        int idx = m * 256 + tid;
        int g = idx >> 7, j4 = idx & 127;
        float f = sc[j4 >> 6][g];
        float4 v = attT4[g * 128 + j4];
        v.x *= f; v.y *= f; v.z *= f; v.w *= f;
        *(float4*)&atls[g * 516 + j4 * 4] = v;
    }
    __syncthreads();

    float* feat = ws + WS_FEAT + (size_t)qi * FEAT;
    const float* raw = ws + WS_RAW;
    const float* vvg = ws + WS_VVG;
    if (tid < 240) {
        if (s == 0 && tid < 192) {
            int g = tid >> 4;
            const float* arow = atls + g * 516;
            float sum = 0.f;
            for (int j4 = 0; j4 < 128; ++j4) {
                float4 a = *(const float4*)&arow[j4 * 4];
                int j = j4 * 4;
                sum = fmaf(a.x, raw[(size_t)(j + 0) * NPROJ + 384 + tid], sum);
                sum = fmaf(a.y, raw[(size_t)(j + 1) * NPROJ + 384 + tid], sum);
                sum = fmaf(a.z, raw[(size_t)(j + 2) * NPROJ + 384 + tid], sum);
                sum = fmaf(a.w, raw[(size_t)(j + 3) * NPROJ + 384 + tid], sum);
            }
            feat[1536 + tid] = sum;
        } else {
            int u = (s == 0) ? (tid - 192) : (48 + tid);
            int lidx = (s == 0) ? (tid - 192) : tid;
            int g = u / 24;
            const float* arow = atls + g * 516;
            float sum = 0.f;
            for (int j4 = 0; j4 < 128; ++j4) {
                float4 a = *(const float4*)&arow[j4 * 4];
                int j = j4 * 4;
                sum = fmaf(a.x, vvg[(size_t)(j + 0) * 288 + u], sum);
                sum = fmaf(a.y, vvg[(size_t)(j + 1) * 288 + u], sum);
                sum = fmaf(a.z, vvg[(size_t)(j + 2) * 288 + u], sum);
                sum = fmaf(a.w, vvg[(size_t)(j + 3) * 288 + u], sum);
            }
            ovecl[lidx] = sum;
        }
    }
    __syncthreads();

    int npts = (s == 0) ? 16 : 80;
    if (tid < npts) {
        int P = (s == 0) ? tid : (16 + tid);
        int u0l = (s == 0) ? (P * 3) : (P * 3 - 48);
        const float* R = rots + qi * 9;
        float t0 = trans[qi * 3 + 0] * 0.1f;
        float t1 = trans[qi * 3 + 1] * 0.1f;
        float t2 = trans[qi * 3 + 2] * 0.1f;
        float d0 = ovecl[u0l + 0] - t0;
        float d1 = ovecl[u0l + 1] - t1;
        float d2 = ovecl[u0l + 2] - t2;
        float o0 = R[0] * d0 + R[3] * d1 + R[6] * d2;
        float o1 = R[1] * d0 + R[4] * d1 + R[7] * d2;
        float o2 = R[2] * d0 + R[5] * d1 + R[8] * d2;
        feat[1728 + P * 3 + 0] = o0;
        feat[1728 + P * 3 + 1] = o1;
        feat[1728 + P * 3 + 2] = o2;
        feat[2016 + P] = sqrtf(o0 * o0 + o1 * o1 + o2 * o2 + 1e-8f);
    }
}

// ---------------- K4: feat @ Wout — LDS-tiled GEMM, split-K x3 ----------------
__global__ __launch_bounds__(256) void k4_gemm(const float* __restrict__ Wout,
                                               float* __restrict__ ws)
{
    __shared__ float As[64][68];
    __shared__ float Bs[64][48];
    const int tid = threadIdx.x;
    const int cc = blockIdx.x >> 6;
    const int t  = blockIdx.x & 63;
    const int l0 = (t >> 3) * 64;
    const int col0 = (t & 7) * 48;
    const float* feat = ws + WS_FEAT;

    const int tx = tid & 15, ty = tid >> 4;
    float acc[4][3];
#pragma unroll
    for (int r = 0; r < 4; ++r)
#pragma unroll
        for (int c = 0; c < 3; ++c) acc[r][c] = 0.f;

    for (int kc = cc * 11; kc < cc * 11 + 11; ++kc) {
        __syncthreads();
#pragma unroll
        for (int pass = 0; pass < 4; ++pass) {
            int m = (tid >> 4) + pass * 16;
            int kk = (tid & 15) * 4;
            const float4 a = *(const float4*)(feat + (size_t)(l0 + m) * FEAT + kc * 64 + kk);
            As[kk + 0][m] = a.x; As[kk + 1][m] = a.y;
            As[kk + 2][m] = a.z; As[kk + 3][m] = a.w;
        }
#pragma unroll
        for (int p = 0; p < 12; ++p) {
            int idx = p * 256 + tid;
            int kk = idx / 48, c = idx - kk * 48;
            Bs[kk][c] = Wout[(size_t)(kc * 64 + kk) * CN + col0 + c];
        }
        __syncthreads();
#pragma unroll 8
        for (int kk = 0; kk < 64; ++kk) {
            const float4 av = *(const float4*)&As[kk][tx * 4];
            const float b0 = Bs[kk][ty * 3 + 0];
            const float b1 = Bs[kk][ty * 3 + 1];
            const float b2 = Bs[kk][ty * 3 + 2];
            acc[0][0] = fmaf(av.x, b0, acc[0][0]); acc[0][1] = fmaf(av.x, b1, acc[0][1]); acc[0][2] = fmaf(av.x, b2, acc[0][2]);
            acc[1][0] = fmaf(av.y, b0, acc[1][0]); acc[1][1] = fmaf(av.y, b1, acc[1][1]); acc[1][2] = fmaf(av.y, b2, acc[1][2]);
            acc[2][0] = fmaf(av.z, b0, acc[2][0]); acc[2][1] = fmaf(av.z, b1, acc[2][1]); acc[2][2] = fmaf(av.z, b2, acc[2][2]);
            acc[3][0] = fmaf(av.w, b0, acc[3][0]); acc[3][1] = fmaf(av.w, b1, acc[3][1]); acc[3][2] = fmaf(av.w, b2, acc[3][2]);
        }
    }
    float* part = ws + WS_PART + (size_t)cc * LQ * CN;
#pragma unroll
    for (int r = 0; r < 4; ++r)
#pragma unroll
        for (int c = 0; c < 3; ++c)
            part[(size_t)(l0 + tx * 4 + r) * CN + col0 + ty * 3 + c] = acc[r][c];
}

// ---------------- K5: reduce partials + bias ----------------
__global__ __launch_bounds__(384) void k5_red(const float* __restrict__ bout,
                                              const float* __restrict__ wsc,
                                              float* __restrict__ out)
{
    const int i = blockIdx.x, n = threadIdx.x;
    const float* part = wsc + WS_PART;
    size_t idx = (size_t)i * CN + n;
    size_t st = (size_t)LQ * CN;
    out[idx] = part[idx] + part[st + idx] + part[2 * st + idx] + bout[n];
}

extern "C" void kernel_launch(void* const* d_in, const int* in_sizes, int n_in,
                              void* d_out, int out_size, void* d_ws, size_t ws_size,
                              hipStream_t stream) {
    const float* Node  = (const float*)d_in[0];
    const float* Edge  = (const float*)d_in[1];
    const float* rots  = (const float*)d_in[2];
    const float* trans = (const float*)d_in[3];
    const float* Wq    = (const float*)d_in[4];
    const float* Wk    = (const float*)d_in[5];
    const float* Wv    = (const float*)d_in[6];
    const float* Wqv   = (const float*)d_in[7];
    const float* Wkv   = (const float*)d_in[8];
    const float* Wvv   = (const float*)d_in[9];
    const float* Wbias = (const float*)d_in[10];
    const float* gamma = (const float*)d_in[11];
    const float* Wout  = (const float*)d_in[12];
    const float* bout  = (const float*)d_in[13];
    float* ws = (float*)d_ws;

    k1a_gemm<<<192, 256, 0, stream>>>(Node, Wq, Wk, Wv, Wqv, Wkv, Wvv, ws);
    k1b_vec<<<512, 256, 0, stream>>>(rots, trans, ws);
    k2_attn<<<1024, 256, 0, stream>>>(Edge, Wbias, gamma, ws);
    k3a_oedge<<<512, 256, 0, stream>>>(Edge, ws);
    k3b_rest<<<1024, 256, 0, stream>>>(rots, trans, ws);
    k4_gemm<<<192, 256, 0, stream>>>(Wout, ws);
    k5_red<<<512, 384, 0, stream>>>(bout, ws, (float*)d_out);
}